// Round 6
// baseline (930.589 us; speedup 1.0000x reference)
//
#include <hip/hip_runtime.h>

// ---------------------------------------------------------------------------
// Swin block, MI355X. ALL I/O fp32 (per reference); bf16 MFMA compute inside.
//   W0: weights fp32 -> bf16 TILED [R/16][K/32][16][32] into d_ws (guarded).
//   K1: fused LN1+shift+QKV(N=384, 4 heads/phase)+serial attention on 4 waves.
//       q/k/v staged fp32 in LDS (no unpack in inner loop), q pre-scaled,
//       __any-guarded rescale skip. 127KB LDS -> 1 block/CU.
//   K2: proj + residual, 64 rows/block, B-prefetch rotation.
//   K3: M=64 rows/block, hidden chunked 8x192, B-prefetch, 76KB LDS.
// B=64 H=W=28 DIM=384 HEADS=12 HD=32 WIN=7 SHIFT=3 N=49 NW=16 HID=1536
// ---------------------------------------------------------------------------

using u16 = unsigned short;
typedef __bf16 bf16x8 __attribute__((ext_vector_type(8)));
typedef float  f32x4  __attribute__((ext_vector_type(4)));

__device__ __forceinline__ float bf2f(u16 u) {
  unsigned x = ((unsigned)u) << 16; return __builtin_bit_cast(float, x);
}
__device__ __forceinline__ u16 f2bf(float f) {
  unsigned x = __builtin_bit_cast(unsigned, f);
  x += 0x7fffu + ((x >> 16) & 1u);   // RNE
  return (u16)(x >> 16);
}
__device__ __forceinline__ int region3(int s) { return s < 21 ? 0 : (s < 25 ? 1 : 2); }
__device__ __forceinline__ void unpack8(uint4 u, float* d) {
  d[0] = bf2f(u.x & 0xffff); d[1] = bf2f(u.x >> 16);
  d[2] = bf2f(u.y & 0xffff); d[3] = bf2f(u.y >> 16);
  d[4] = bf2f(u.z & 0xffff); d[5] = bf2f(u.z >> 16);
  d[6] = bf2f(u.w & 0xffff); d[7] = bf2f(u.w >> 16);
}
__device__ __forceinline__ uint4 pack8f(const float* p) {
  float4 a = *(const float4*)p, b = *(const float4*)(p + 4);
  uint4 u;
  u.x = (unsigned)f2bf(a.x) | ((unsigned)f2bf(a.y) << 16);
  u.y = (unsigned)f2bf(a.z) | ((unsigned)f2bf(a.w) << 16);
  u.z = (unsigned)f2bf(b.x) | ((unsigned)f2bf(b.y) << 16);
  u.w = (unsigned)f2bf(b.z) | ((unsigned)f2bf(b.w) << 16);
  return u;
}
// 8 consecutive fp32 -> bf16x8 MFMA fragment (fallback path only)
__device__ __forceinline__ bf16x8 ldw8(const float* p) {
  float4 a = *(const float4*)p, b = *(const float4*)(p + 4);
  bf16x8 r;
  r[0] = __builtin_bit_cast(__bf16, f2bf(a.x));
  r[1] = __builtin_bit_cast(__bf16, f2bf(a.y));
  r[2] = __builtin_bit_cast(__bf16, f2bf(a.z));
  r[3] = __builtin_bit_cast(__bf16, f2bf(a.w));
  r[4] = __builtin_bit_cast(__bf16, f2bf(b.x));
  r[5] = __builtin_bit_cast(__bf16, f2bf(b.y));
  r[6] = __builtin_bit_cast(__bf16, f2bf(b.z));
  r[7] = __builtin_bit_cast(__bf16, f2bf(b.w));
  return r;
}
// tanh-form GELU
__device__ __forceinline__ float gelu_f(float v) {
  float u = v * (0.7978845608028654f + 0.0356774081f * v * v);
  float e = __expf(2.f * u);
  float t = 1.f - 2.f / (e + 1.f);
  return 0.5f * v * (1.f + t);
}

// ---------------------------------------------------------------------------
// W0: fp32 [R][K] row-major -> bf16 tiled [R/16][K/32][16][32]
// ---------------------------------------------------------------------------
__global__ __launch_bounds__(256) void repack_kernel(
    const float* __restrict__ src, u16* __restrict__ dst, int R, int K)
{
  int i = blockIdx.x * 256 + threadIdx.x;
  int n8 = (R * K) >> 3;
  if (i >= n8) return;
  int e = i * 8;
  int r = e / K, c = e - (e / K) * K;
  size_t off = ((((size_t)(r >> 4)) * (K >> 5) + (c >> 5)) << 9) + (r & 15) * 32 + (c & 31);
  *(uint4*)&dst[off] = pack8f(src + (size_t)r * K + c);
}

// ---------------------------------------------------------------------------
// K1: per-window fused LN1 + QKV + attention.
// 3 phases x 4 heads. GEMM N=384 (proj-shape), epilogue -> fp32 qf LDS.
// LDS: xin 50,176 + qf 76,048 + mustd 392 = 126,616 B -> 1 block/CU.
// qf layout: [row 0..48][wave*96 + part*32 + d], stride 388 f32 (bank-skewed).
// ---------------------------------------------------------------------------
template<bool BF>
__global__ __launch_bounds__(256, 1) void win_attn_kernel(
    const float* __restrict__ x, const float* __restrict__ n1w, const float* __restrict__ n1b,
    const void* __restrict__ qkv_w, const float* __restrict__ qkv_b,
    const float* __restrict__ btab, float* __restrict__ out)
{
  __shared__ __align__(16) u16 xin[64 * 392];     // 50,176 B
  __shared__ __align__(16) float qf[49 * 388];    // 76,048 B
  __shared__ float mustd[98];

  const int tid  = threadIdx.x;
  const int lane = tid & 63;
  const int wave = tid >> 6;
  const int quad = lane >> 4;
  const int r16  = lane & 15;

  const int win  = blockIdx.x;
  const int bimg = win >> 4;
  const int wi   = win & 15;
  const int wwh  = wi >> 2, www = wi & 3;

  for (int e = tid * 8; e < 15 * 392; e += 2048)
    *(uint4*)&xin[49 * 392 + e] = make_uint4(0, 0, 0, 0);

  for (int e = tid * 8; e < 49 * 384; e += 2048) {
    int r = e / 384, c = e - (e / 384) * 384;
    int i = r / 7, j = r - (r / 7) * 7;
    int h  = wwh * 7 + i + 3; if (h  >= 28) h  -= 28;
    int w2 = www * 7 + j + 3; if (w2 >= 28) w2 -= 28;
    *(uint4*)&xin[r * 392 + c] =
        pack8f(x + ((size_t)(bimg * 784 + h * 28 + w2)) * 384 + c);
  }
  __syncthreads();

  for (int r = wave; r < 49; r += 4) {
    float v[6]; float s = 0.f;
#pragma unroll
    for (int k = 0; k < 6; ++k) { v[k] = bf2f(xin[r * 392 + lane + k * 64]); s += v[k]; }
#pragma unroll
    for (int off = 32; off; off >>= 1) s += __shfl_xor(s, off);
    float mu = s * (1.f / 384.f);
    float vs = 0.f;
#pragma unroll
    for (int k = 0; k < 6; ++k) { float d = v[k] - mu; vs += d * d; }
#pragma unroll
    for (int off = 32; off; off >>= 1) vs += __shfl_xor(vs, off);
    if (lane == 0) { mustd[r] = mu; mustd[49 + r] = rsqrtf(vs * (1.f / 384.f) + 1e-5f); }
  }
  __syncthreads();

  for (int e = tid * 8; e < 49 * 384; e += 2048) {
    int r = e / 384, c = e - (e / 384) * 384;
    float mu = mustd[r], rs = mustd[49 + r];
    float v[8];
    unpack8(*(uint4*)&xin[r * 392 + c], v);
    float4 w0 = *(const float4*)(n1w + c), w1 = *(const float4*)(n1w + c + 4);
    float4 b0 = *(const float4*)(n1b + c), b1 = *(const float4*)(n1b + c + 4);
    float wv[8] = {w0.x, w0.y, w0.z, w0.w, w1.x, w1.y, w1.z, w1.w};
    float bv[8] = {b0.x, b0.y, b0.z, b0.w, b1.x, b1.y, b1.z, b1.w};
    unsigned pk[4];
#pragma unroll
    for (int i = 0; i < 4; ++i) {
      u16 a = f2bf((v[2*i]   - mu) * rs * wv[2*i]   + bv[2*i]);
      u16 b = f2bf((v[2*i+1] - mu) * rs * wv[2*i+1] + bv[2*i+1]);
      pk[i] = (unsigned)a | ((unsigned)b << 16);
    }
    *(uint4*)&xin[r * 392 + c] = make_uint4(pk[0], pk[1], pk[2], pk[3]);
  }
  __syncthreads();

  // query-side geometry (lane = query row)
  const int i1 = (lane < 49 ? lane : 48) / 7;
  const int j1 = (lane < 49 ? lane : 48) - i1 * 7;
  const int rid1 = region3(wwh * 7 + i1) * 3 + region3(www * 7 + j1);

  // 3 phases x 4 heads; wave w owns head it*4+w
  for (int it = 0; it < 3; ++it) {
    const int hh = it * 4 + wave;
    // ---- QKV GEMM: N=384 cols; col = wave*96 + nt*16 + r16 ----
    f32x4 acc[4][6];
#pragma unroll
    for (int a = 0; a < 4; ++a)
#pragma unroll
      for (int c = 0; c < 6; ++c) acc[a][c] = (f32x4){0.f, 0.f, 0.f, 0.f};

    auto loadB = [&](int nt, int kt) -> bf16x8 {
      int part = nt >> 1;                       // 0=q 1=k 2=v
      if constexpr (BF) {
        int rt = part * 24 + hh * 2 + (nt & 1);
        return *(const bf16x8*)((const u16*)qkv_w +
               ((((size_t)rt) * 12 + kt) << 9) + r16 * 32 + quad * 8);
      } else {
        int f = part * 384 + hh * 32 + (nt & 1) * 16 + r16;
        return ldw8((const float*)qkv_w + (size_t)f * 384 + kt * 32 + quad * 8);
      }
    };

    bf16x8 bc[6];
#pragma unroll
    for (int nt = 0; nt < 6; ++nt) bc[nt] = loadB(nt, 0);
    for (int kt = 0; kt < 12; ++kt) {
      bf16x8 bn[6];
      if (kt < 11) {
#pragma unroll
        for (int nt = 0; nt < 6; ++nt) bn[nt] = loadB(nt, kt + 1);
      }
      bf16x8 af[4];
#pragma unroll
      for (int mt = 0; mt < 4; ++mt)
        af[mt] = *(const bf16x8*)&xin[(mt * 16 + r16) * 392 + kt * 32 + quad * 8];
#pragma unroll
      for (int nt = 0; nt < 6; ++nt)
#pragma unroll
        for (int mt = 0; mt < 4; ++mt)
          acc[mt][nt] = __builtin_amdgcn_mfma_f32_16x16x32_bf16(af[mt], bc[nt], acc[mt][nt], 0, 0, 0);
      if (kt < 11) {
#pragma unroll
        for (int nt = 0; nt < 6; ++nt) bc[nt] = bn[nt];
      }
    }
    // epilogue: fp32 into qf; q pre-scaled
#pragma unroll
    for (int mt = 0; mt < 4; ++mt) {
#pragma unroll
      for (int nt = 0; nt < 6; ++nt) {
        int part = nt >> 1;
        int dcol = (nt & 1) * 16 + r16;
        int fb   = part * 384 + hh * 32 + dcol;
#pragma unroll
        for (int rg = 0; rg < 4; ++rg) {
          int row = mt * 16 + quad * 4 + rg;
          if (row < 49) {
            float v = acc[mt][nt][rg] + qkv_b[fb];
            if (part == 0) v *= 0.17677669529663689f;
            qf[row * 388 + wave * 96 + part * 32 + dcol] = v;
          }
        }
      }
    }
    __syncthreads();

    // ---- serial attention: all 4 waves, wave w -> head hh ----
    if (lane < 49) {
      const float* base = qf + wave * 96;
      float q[32];
#pragma unroll
      for (int kk = 0; kk < 8; ++kk)
        *(float4*)&q[kk * 4] = *(const float4*)&base[lane * 388 + kk * 4];

      float mx = -3.0e38f, den = 0.f, o[32];
#pragma unroll
      for (int k = 0; k < 32; ++k) o[k] = 0.f;

      for (int m = 0; m < 49; ++m) {
        const float* kr = base + m * 388 + 32;
        float d = 0.f;
#pragma unroll
        for (int k = 0; k < 32; ++k) d += q[k] * kr[k];
        int i2 = m / 7, j2 = m - (m / 7) * 7;
        d += btab[((i1 - i2 + 6) * 13 + (j1 - j2 + 6)) * 12 + hh];
        if (region3(wwh * 7 + i2) * 3 + region3(www * 7 + j2) != rid1) d -= 100.f;
        const float* vr = base + m * 388 + 64;
        bool up = __any(d > mx);
        if (up) {
          float nm = fmaxf(mx, d);
          float sc = __expf(mx - nm);
          float p  = __expf(d - nm);
          den = den * sc + p;
#pragma unroll
          for (int k = 0; k < 32; ++k) o[k] = o[k] * sc + p * vr[k];
          mx = nm;
        } else {
          float p = __expf(d - mx);
          den += p;
#pragma unroll
          for (int k = 0; k < 32; ++k) o[k] += p * vr[k];
        }
      }
      float inv = 1.f / den;
      int h  = wwh * 7 + i1 + 3; if (h  >= 28) h  -= 28;
      int w2 = www * 7 + j1 + 3; if (w2 >= 28) w2 -= 28;
      float* orow = out + ((size_t)(bimg * 784 + h * 28 + w2)) * 384 + hh * 32;
#pragma unroll
      for (int k = 0; k < 8; ++k) {
        float4 f4 = make_float4(o[4*k] * inv, o[4*k+1] * inv, o[4*k+2] * inv, o[4*k+3] * inv);
        *(float4*)&orow[4 * k] = f4;
      }
    }
    __syncthreads();
  }
}

// ---------------------------------------------------------------------------
// K2: proj + residual(x), in-place on d_out (fp32). 64 rows/block.
// ---------------------------------------------------------------------------
template<bool BF>
__global__ __launch_bounds__(256, 3) void proj_kernel(
    const float* attn, const void* __restrict__ proj_w, const float* __restrict__ proj_b,
    const float* __restrict__ x, float* outp)
{
  __shared__ __align__(16) u16 As[64 * 392];
  const int tid  = threadIdx.x;
  const int lane = tid & 63;
  const int wave = tid >> 6;
  const int quad = lane >> 4;
  const int r16  = lane & 15;
  const int bm   = blockIdx.x * 64;

  for (int e = tid * 8; e < 64 * 384; e += 2048) {
    int r = e / 384, c = e - (e / 384) * 384;
    *(uint4*)&As[r * 392 + c] = pack8f(attn + (size_t)(bm + r) * 384 + c);
  }
  __syncthreads();

  f32x4 acc[4][6];
#pragma unroll
  for (int a = 0; a < 4; ++a)
#pragma unroll
    for (int c = 0; c < 6; ++c) acc[a][c] = (f32x4){0.f, 0.f, 0.f, 0.f};

  auto loadB = [&](int nt, int kt) -> bf16x8 {
    if constexpr (BF) {
      return *(const bf16x8*)((const u16*)proj_w +
             ((((size_t)(wave * 6 + nt)) * 12 + kt) << 9) + r16 * 32 + quad * 8);
    } else {
      int n = wave * 96 + nt * 16 + r16;
      return ldw8((const float*)proj_w + (size_t)n * 384 + kt * 32 + quad * 8);
    }
  };

  bf16x8 bc[6];
#pragma unroll
  for (int nt = 0; nt < 6; ++nt) bc[nt] = loadB(nt, 0);
  for (int kt = 0; kt < 12; ++kt) {
    bf16x8 bn[6];
    if (kt < 11) {
#pragma unroll
      for (int nt = 0; nt < 6; ++nt) bn[nt] = loadB(nt, kt + 1);
    }
    bf16x8 af[4];
#pragma unroll
    for (int mt = 0; mt < 4; ++mt)
      af[mt] = *(const bf16x8*)&As[(mt * 16 + r16) * 392 + kt * 32 + quad * 8];
#pragma unroll
    for (int nt = 0; nt < 6; ++nt)
#pragma unroll
      for (int mt = 0; mt < 4; ++mt)
        acc[mt][nt] = __builtin_amdgcn_mfma_f32_16x16x32_bf16(af[mt], bc[nt], acc[mt][nt], 0, 0, 0);
    if (kt < 11) {
#pragma unroll
      for (int nt = 0; nt < 6; ++nt) bc[nt] = bn[nt];
    }
  }
#pragma unroll
  for (int mt = 0; mt < 4; ++mt) {
#pragma unroll
    for (int nt = 0; nt < 6; ++nt) {
#pragma unroll
      for (int rg = 0; rg < 4; ++rg) {
        int gm = bm + mt * 16 + quad * 4 + rg;
        int gn = wave * 96 + nt * 16 + r16;
        float v = acc[mt][nt][rg] + proj_b[gn] + x[(size_t)gm * 384 + gn];
        outp[(size_t)gm * 384 + gn] = v;
      }
    }
  }
}

// ---------------------------------------------------------------------------
// K3: fused LN2 + FC1 + GELU + FC2 + residual, M=64 rows/block.
// Hidden chunked 8x192: LDS = xs 50K + hs 25.6K -> 2 blocks/CU.
// ---------------------------------------------------------------------------
template<bool BF>
__global__ __launch_bounds__(256, 2) void mlp_kernel(
    const float* __restrict__ n2w, const float* __restrict__ n2b,
    const void* __restrict__ fc1_w, const float* __restrict__ fc1_b,
    const void* __restrict__ fc2_w, const float* __restrict__ fc2_b,
    float* xr)
{
  __shared__ __align__(16) u16 xs[64 * 392];   // 50,176 B
  __shared__ __align__(16) u16 hs[64 * 200];   // 25,600 B (one 192-col hidden chunk)
  __shared__ float mustd[128];
  const int tid  = threadIdx.x;
  const int lane = tid & 63;
  const int wave = tid >> 6;
  const int quad = lane >> 4;
  const int r16  = lane & 15;
  const int bm   = blockIdx.x * 64;

  for (int e = tid * 8; e < 64 * 384; e += 2048) {
    int r = e / 384, c = e - (e / 384) * 384;
    *(uint4*)&xs[r * 392 + c] = pack8f(xr + (size_t)(bm + r) * 384 + c);
  }
  __syncthreads();

  for (int r = wave; r < 64; r += 4) {
    float v[6]; float s = 0.f;
#pragma unroll
    for (int k = 0; k < 6; ++k) { v[k] = bf2f(xs[r * 392 + lane + k * 64]); s += v[k]; }
#pragma unroll
    for (int off = 32; off; off >>= 1) s += __shfl_xor(s, off);
    float mu = s * (1.f / 384.f);
    float vs = 0.f;
#pragma unroll
    for (int k = 0; k < 6; ++k) { float d = v[k] - mu; vs += d * d; }
#pragma unroll
    for (int off = 32; off; off >>= 1) vs += __shfl_xor(vs, off);
    if (lane == 0) { mustd[r] = mu; mustd[64 + r] = rsqrtf(vs * (1.f / 384.f) + 1e-5f); }
  }
  __syncthreads();

  for (int e = tid * 8; e < 64 * 384; e += 2048) {
    int r = e / 384, c = e - (e / 384) * 384;
    float mu = mustd[r], rs = mustd[64 + r];
    float v[8];
    unpack8(*(uint4*)&xs[r * 392 + c], v);
    float4 w0 = *(const float4*)(n2w + c), w1 = *(const float4*)(n2w + c + 4);
    float4 b0 = *(const float4*)(n2b + c), b1 = *(const float4*)(n2b + c + 4);
    float wv[8] = {w0.x, w0.y, w0.z, w0.w, w1.x, w1.y, w1.z, w1.w};
    float bv[8] = {b0.x, b0.y, b0.z, b0.w, b1.x, b1.y, b1.z, b1.w};
    unsigned pk[4];
#pragma unroll
    for (int i = 0; i < 4; ++i) {
      u16 a = f2bf((v[2*i]   - mu) * rs * wv[2*i]   + bv[2*i]);
      u16 b = f2bf((v[2*i+1] - mu) * rs * wv[2*i+1] + bv[2*i+1]);
      pk[i] = (unsigned)a | ((unsigned)b << 16);
    }
    *(uint4*)&xs[r * 392 + c] = make_uint4(pk[0], pk[1], pk[2], pk[3]);
  }
  __syncthreads();

  // FC2 accumulators persist across hidden chunks
  f32x4 acc2[4][6];
#pragma unroll
  for (int a = 0; a < 4; ++a)
#pragma unroll
    for (int c = 0; c < 6; ++c) acc2[a][c] = (f32x4){0.f, 0.f, 0.f, 0.f};

  for (int hc = 0; hc < 8; ++hc) {
    // --- FC1 chunk: 64 rows x 192 hidden cols (wave owns 48 cols = 3 nt) ---
    f32x4 acc1[4][3];
#pragma unroll
    for (int a = 0; a < 4; ++a)
#pragma unroll
      for (int c = 0; c < 3; ++c) acc1[a][c] = (f32x4){0.f, 0.f, 0.f, 0.f};

    auto loadB1 = [&](int nt, int kt) -> bf16x8 {
      if constexpr (BF) {
        int rt = hc * 12 + wave * 3 + nt;
        return *(const bf16x8*)((const u16*)fc1_w +
               ((((size_t)rt) * 12 + kt) << 9) + r16 * 32 + quad * 8);
      } else {
        int ng = hc * 192 + wave * 48 + nt * 16 + r16;
        return ldw8((const float*)fc1_w + (size_t)ng * 384 + kt * 32 + quad * 8);
      }
    };
    {
      bf16x8 bc[3];
#pragma unroll
      for (int nt = 0; nt < 3; ++nt) bc[nt] = loadB1(nt, 0);
      for (int kt = 0; kt < 12; ++kt) {
        bf16x8 bn[3];
        if (kt < 11) {
#pragma unroll
          for (int nt = 0; nt < 3; ++nt) bn[nt] = loadB1(nt, kt + 1);
        }
        bf16x8 af[4];
#pragma unroll
        for (int mt = 0; mt < 4; ++mt)
          af[mt] = *(const bf16x8*)&xs[(mt * 16 + r16) * 392 + kt * 32 + quad * 8];
#pragma unroll
        for (int nt = 0; nt < 3; ++nt)
#pragma unroll
          for (int mt = 0; mt < 4; ++mt)
            acc1[mt][nt] = __builtin_amdgcn_mfma_f32_16x16x32_bf16(af[mt], bc[nt], acc1[mt][nt], 0, 0, 0);
        if (kt < 11) {
#pragma unroll
          for (int nt = 0; nt < 3; ++nt) bc[nt] = bn[nt];
        }
      }
    }
    __syncthreads();   // prev chunk's FC2 reads of hs complete
    // --- GELU -> hs ---
#pragma unroll
    for (int mt = 0; mt < 4; ++mt) {
#pragma unroll
      for (int nt = 0; nt < 3; ++nt) {
#pragma unroll
        for (int rg = 0; rg < 4; ++rg) {
          int row = mt * 16 + quad * 4 + rg;
          int nl  = wave * 48 + nt * 16 + r16;
          float v = acc1[mt][nt][rg] + fc1_b[hc * 192 + nl];
          hs[row * 200 + nl] = f2bf(gelu_f(v));
        }
      }
    }
    __syncthreads();
    // --- FC2 partial over this chunk (k = 192, 6 k-steps) ---
    auto loadB2 = [&](int nt, int kk) -> bf16x8 {
      if constexpr (BF) {
        int rt = wave * 6 + nt;
        return *(const bf16x8*)((const u16*)fc2_w +
               ((((size_t)rt) * 48 + hc * 6 + kk) << 9) + r16 * 32 + quad * 8);
      } else {
        int n = wave * 96 + nt * 16 + r16;
        return ldw8((const float*)fc2_w + (size_t)n * 1536 + hc * 192 + kk * 32 + quad * 8);
      }
    };
    {
      bf16x8 bc[6];
#pragma unroll
      for (int nt = 0; nt < 6; ++nt) bc[nt] = loadB2(nt, 0);
      for (int kk = 0; kk < 6; ++kk) {
        bf16x8 bn[6];
        if (kk < 5) {
#pragma unroll
          for (int nt = 0; nt < 6; ++nt) bn[nt] = loadB2(nt, kk + 1);
        }
        bf16x8 af[4];
#pragma unroll
        for (int mt = 0; mt < 4; ++mt)
          af[mt] = *(const bf16x8*)&hs[(mt * 16 + r16) * 200 + kk * 32 + quad * 8];
#pragma unroll
        for (int nt = 0; nt < 6; ++nt)
#pragma unroll
          for (int mt = 0; mt < 4; ++mt)
            acc2[mt][nt] = __builtin_amdgcn_mfma_f32_16x16x32_bf16(af[mt], bc[nt], acc2[mt][nt], 0, 0, 0);
        if (kk < 5) {
#pragma unroll
          for (int nt = 0; nt < 6; ++nt) bc[nt] = bn[nt];
        }
      }
    }
  }

  // FC2 bias + residual (in-place, fp32)
#pragma unroll
  for (int mt = 0; mt < 4; ++mt) {
#pragma unroll
    for (int nt = 0; nt < 6; ++nt) {
#pragma unroll
      for (int rg = 0; rg < 4; ++rg) {
        int gm = bm + mt * 16 + quad * 4 + rg;
        int gn = wave * 96 + nt * 16 + r16;
        size_t g = (size_t)gm * 384 + gn;
        xr[g] = acc2[mt][nt][rg] + fc2_b[gn] + xr[g];
      }
    }
  }
}

// ---------------------------------------------------------------------------
extern "C" void kernel_launch(void* const* d_in, const int* in_sizes, int n_in,
                              void* d_out, int out_size, void* d_ws, size_t ws_size,
                              hipStream_t stream) {
  const float* x      = (const float*)d_in[0];
  const float* n1w    = (const float*)d_in[1];
  const float* n1b    = (const float*)d_in[2];
  const float* qkv_w  = (const float*)d_in[3];
  const float* qkv_b  = (const float*)d_in[4];
  const float* proj_w = (const float*)d_in[5];
  const float* proj_b = (const float*)d_in[6];
  const float* btab   = (const float*)d_in[7];
  const float* n2w    = (const float*)d_in[8];
  const float* n2b    = (const float*)d_in[9];
  const float* fc1_w  = (const float*)d_in[10];
  const float* fc1_b  = (const float*)d_in[11];
  const float* fc2_w  = (const float*)d_in[12];
  const float* fc2_b  = (const float*)d_in[13];

  float* dout = (float*)d_out;
  (void)in_sizes; (void)n_in; (void)out_size;

  const size_t NQ = 442368, NP = 147456, N1 = 589824, N2 = 589824;
  const size_t need = (NQ + NP + N1 + N2) * sizeof(u16);   // 3,538,944 B

  if (d_ws && ws_size >= need) {
    u16* wq = (u16*)d_ws;
    u16* wp = wq + NQ;
    u16* w1 = wp + NP;
    u16* w2 = w1 + N1;
    repack_kernel<<<(int)((NQ / 8 + 255) / 256), 256, 0, stream>>>(qkv_w,  wq, 1152, 384);
    repack_kernel<<<(int)((NP / 8 + 255) / 256), 256, 0, stream>>>(proj_w, wp, 384, 384);
    repack_kernel<<<(int)((N1 / 8 + 255) / 256), 256, 0, stream>>>(fc1_w,  w1, 1536, 384);
    repack_kernel<<<(int)((N2 / 8 + 255) / 256), 256, 0, stream>>>(fc2_w,  w2, 384, 1536);

    win_attn_kernel<true><<<1024, 256, 0, stream>>>(x, n1w, n1b, wq, qkv_b, btab, dout);
    proj_kernel<true><<<784, 256, 0, stream>>>(dout, wp, proj_b, x, dout);
    mlp_kernel<true><<<784, 256, 0, stream>>>(n2w, n2b, w1, fc1_b, w2, fc2_b, dout);
  } else {
    win_attn_kernel<false><<<1024, 256, 0, stream>>>(x, n1w, n1b, qkv_w, qkv_b, btab, dout);
    proj_kernel<false><<<784, 256, 0, stream>>>(dout, proj_w, proj_b, x, dout);
    mlp_kernel<false><<<784, 256, 0, stream>>>(n2w, n2b, fc1_w, fc1_b, fc2_w, fc2_b, dout);
  }
}

// Round 7
// 825.738 us; speedup vs baseline: 1.1270x; 1.1270x over previous
//
#include <hip/hip_runtime.h>

// ---------------------------------------------------------------------------
// Swin block, MI355X. ALL I/O fp32 (per reference); bf16 MFMA compute inside.
//   W0: weights fp32 -> bf16 TILED [R/16][K/32][16][32] into d_ws (guarded).
//   K1: fused LN1+shift+QKV (6 phases x 2 heads) + key-split attention:
//       wave = (head, key-half), 25-iter serial loop, flash-merge via LDS.
//       76.8KB LDS -> 2 blocks/CU. Pipelined k-row + bias prefetch.
//   K2: proj + residual, 64 rows/block, B-prefetch rotation.
//   K3: M=64 rows/block, hidden chunked 8x192, B-prefetch, 76KB LDS.
// B=64 H=W=28 DIM=384 HEADS=12 HD=32 WIN=7 SHIFT=3 N=49 NW=16 HID=1536
// ---------------------------------------------------------------------------

using u16 = unsigned short;
typedef __bf16 bf16x8 __attribute__((ext_vector_type(8)));
typedef float  f32x4  __attribute__((ext_vector_type(4)));

__device__ __forceinline__ float bf2f(u16 u) {
  unsigned x = ((unsigned)u) << 16; return __builtin_bit_cast(float, x);
}
__device__ __forceinline__ u16 f2bf(float f) {
  unsigned x = __builtin_bit_cast(unsigned, f);
  x += 0x7fffu + ((x >> 16) & 1u);   // RNE
  return (u16)(x >> 16);
}
__device__ __forceinline__ int region3(int s) { return s < 21 ? 0 : (s < 25 ? 1 : 2); }
__device__ __forceinline__ void unpack8(uint4 u, float* d) {
  d[0] = bf2f(u.x & 0xffff); d[1] = bf2f(u.x >> 16);
  d[2] = bf2f(u.y & 0xffff); d[3] = bf2f(u.y >> 16);
  d[4] = bf2f(u.z & 0xffff); d[5] = bf2f(u.z >> 16);
  d[6] = bf2f(u.w & 0xffff); d[7] = bf2f(u.w >> 16);
}
__device__ __forceinline__ uint4 pack8f(const float* p) {
  float4 a = *(const float4*)p, b = *(const float4*)(p + 4);
  uint4 u;
  u.x = (unsigned)f2bf(a.x) | ((unsigned)f2bf(a.y) << 16);
  u.y = (unsigned)f2bf(a.z) | ((unsigned)f2bf(a.w) << 16);
  u.z = (unsigned)f2bf(b.x) | ((unsigned)f2bf(b.y) << 16);
  u.w = (unsigned)f2bf(b.z) | ((unsigned)f2bf(b.w) << 16);
  return u;
}
// 8 consecutive fp32 -> bf16x8 MFMA fragment (fallback path only)
__device__ __forceinline__ bf16x8 ldw8(const float* p) {
  float4 a = *(const float4*)p, b = *(const float4*)(p + 4);
  bf16x8 r;
  r[0] = __builtin_bit_cast(__bf16, f2bf(a.x));
  r[1] = __builtin_bit_cast(__bf16, f2bf(a.y));
  r[2] = __builtin_bit_cast(__bf16, f2bf(a.z));
  r[3] = __builtin_bit_cast(__bf16, f2bf(a.w));
  r[4] = __builtin_bit_cast(__bf16, f2bf(b.x));
  r[5] = __builtin_bit_cast(__bf16, f2bf(b.y));
  r[6] = __builtin_bit_cast(__bf16, f2bf(b.z));
  r[7] = __builtin_bit_cast(__bf16, f2bf(b.w));
  return r;
}
// tanh-form GELU
__device__ __forceinline__ float gelu_f(float v) {
  float u = v * (0.7978845608028654f + 0.0356774081f * v * v);
  float e = __expf(2.f * u);
  float t = 1.f - 2.f / (e + 1.f);
  return 0.5f * v * (1.f + t);
}

// ---------------------------------------------------------------------------
// W0: fp32 [R][K] row-major -> bf16 tiled [R/16][K/32][16][32]
// ---------------------------------------------------------------------------
__global__ __launch_bounds__(256) void repack_kernel(
    const float* __restrict__ src, u16* __restrict__ dst, int R, int K)
{
  int i = blockIdx.x * 256 + threadIdx.x;
  int n8 = (R * K) >> 3;
  if (i >= n8) return;
  int e = i * 8;
  int r = e / K, c = e - (e / K) * K;
  size_t off = ((((size_t)(r >> 4)) * (K >> 5) + (c >> 5)) << 9) + (r & 15) * 32 + (c & 31);
  *(uint4*)&dst[off] = pack8f(src + (size_t)r * K + c);
}

// ---------------------------------------------------------------------------
// K1: per-window fused LN1 + QKV + key-split attention.
// 6 phases x 2 heads; wave w = (head w>>1, key-half w&1), 25-iter loop.
// LDS: xin 50,176 + qkvs 18,816 + po 6,664 + pm 784 + mustd 392 = 76,832 B
//   -> 2 blocks/CU (8 waves/CU).
// ---------------------------------------------------------------------------
template<bool BF>
__global__ __launch_bounds__(256, 2) void win_attn_kernel(
    const float* __restrict__ x, const float* __restrict__ n1w, const float* __restrict__ n1b,
    const void* __restrict__ qkv_w, const float* __restrict__ qkv_b,
    const float* __restrict__ btab, float* __restrict__ out)
{
  __shared__ __align__(16) u16 xin[64 * 392];    // 50,176 B
  __shared__ __align__(16) u16 qkvs[49 * 192];   // 18,816 B
  __shared__ __align__(16) u16 po[2][49][34];    //  6,664 B partial O (bf16)
  __shared__ float pm[2][98];                    //    784 B partial (mx,den)
  __shared__ float mustd[98];

  const int tid  = threadIdx.x;
  const int lane = tid & 63;
  const int wave = tid >> 6;
  const int quad = lane >> 4;
  const int r16  = lane & 15;

  const int win  = blockIdx.x;
  const int bimg = win >> 4;
  const int wi   = win & 15;
  const int wwh  = wi >> 2, www = wi & 3;

  for (int e = tid * 8; e < 15 * 392; e += 2048)
    *(uint4*)&xin[49 * 392 + e] = make_uint4(0, 0, 0, 0);

  for (int e = tid * 8; e < 49 * 384; e += 2048) {
    int r = e / 384, c = e - (e / 384) * 384;
    int i = r / 7, j = r - (r / 7) * 7;
    int h  = wwh * 7 + i + 3; if (h  >= 28) h  -= 28;
    int w2 = www * 7 + j + 3; if (w2 >= 28) w2 -= 28;
    *(uint4*)&xin[r * 392 + c] =
        pack8f(x + ((size_t)(bimg * 784 + h * 28 + w2)) * 384 + c);
  }
  __syncthreads();

  for (int r = wave; r < 49; r += 4) {
    float v[6]; float s = 0.f;
#pragma unroll
    for (int k = 0; k < 6; ++k) { v[k] = bf2f(xin[r * 392 + lane + k * 64]); s += v[k]; }
#pragma unroll
    for (int off = 32; off; off >>= 1) s += __shfl_xor(s, off);
    float mu = s * (1.f / 384.f);
    float vs = 0.f;
#pragma unroll
    for (int k = 0; k < 6; ++k) { float d = v[k] - mu; vs += d * d; }
#pragma unroll
    for (int off = 32; off; off >>= 1) vs += __shfl_xor(vs, off);
    if (lane == 0) { mustd[r] = mu; mustd[49 + r] = rsqrtf(vs * (1.f / 384.f) + 1e-5f); }
  }
  __syncthreads();

  for (int e = tid * 8; e < 49 * 384; e += 2048) {
    int r = e / 384, c = e - (e / 384) * 384;
    float mu = mustd[r], rs = mustd[49 + r];
    float v[8];
    unpack8(*(uint4*)&xin[r * 392 + c], v);
    float4 w0 = *(const float4*)(n1w + c), w1 = *(const float4*)(n1w + c + 4);
    float4 b0 = *(const float4*)(n1b + c), b1 = *(const float4*)(n1b + c + 4);
    float wv[8] = {w0.x, w0.y, w0.z, w0.w, w1.x, w1.y, w1.z, w1.w};
    float bv[8] = {b0.x, b0.y, b0.z, b0.w, b1.x, b1.y, b1.z, b1.w};
    unsigned pk[4];
#pragma unroll
    for (int i = 0; i < 4; ++i) {
      u16 a = f2bf((v[2*i]   - mu) * rs * wv[2*i]   + bv[2*i]);
      u16 b = f2bf((v[2*i+1] - mu) * rs * wv[2*i+1] + bv[2*i+1]);
      pk[i] = (unsigned)a | ((unsigned)b << 16);
    }
    *(uint4*)&xin[r * 392 + c] = make_uint4(pk[0], pk[1], pk[2], pk[3]);
  }
  __syncthreads();

  // query-side geometry (lane = query row)
  const int i1 = (lane < 49 ? lane : 48) / 7;
  const int j1 = (lane < 49 ? lane : 48) - i1 * 7;
  const int rid1 = region3(wwh * 7 + i1) * 3 + region3(www * 7 + j1);

  for (int hp = 0; hp < 6; ++hp) {
    // ---- QKV GEMM for 2 heads (N=192), B-prefetch rotation ----
    f32x4 acc[4][3];
#pragma unroll
    for (int a = 0; a < 4; ++a)
#pragma unroll
      for (int c = 0; c < 3; ++c) acc[a][c] = (f32x4){0.f, 0.f, 0.f, 0.f};

    auto loadB = [&](int nt, int kt) -> bf16x8 {
      if constexpr (BF) {
        int n_noR = wave * 48 + nt * 16;
        int ftile = (n_noR >> 6) * 24 + hp * 4 + ((n_noR >> 4) & 3);
        return *(const bf16x8*)((const u16*)qkv_w +
               ((((size_t)ftile) * 12 + kt) << 9) + r16 * 32 + quad * 8);
      } else {
        int n = wave * 48 + nt * 16 + r16;
        int f = (n >> 6) * 384 + hp * 64 + (n & 63);
        return ldw8((const float*)qkv_w + (size_t)f * 384 + kt * 32 + quad * 8);
      }
    };

    bf16x8 bc[3];
#pragma unroll
    for (int nt = 0; nt < 3; ++nt) bc[nt] = loadB(nt, 0);
    for (int kt = 0; kt < 12; ++kt) {
      bf16x8 bn[3];
      if (kt < 11) {
#pragma unroll
        for (int nt = 0; nt < 3; ++nt) bn[nt] = loadB(nt, kt + 1);
      }
      bf16x8 af[4];
#pragma unroll
      for (int mt = 0; mt < 4; ++mt)
        af[mt] = *(const bf16x8*)&xin[(mt * 16 + r16) * 392 + kt * 32 + quad * 8];
#pragma unroll
      for (int nt = 0; nt < 3; ++nt)
#pragma unroll
        for (int mt = 0; mt < 4; ++mt)
          acc[mt][nt] = __builtin_amdgcn_mfma_f32_16x16x32_bf16(af[mt], bc[nt], acc[mt][nt], 0, 0, 0);
      if (kt < 11) {
#pragma unroll
        for (int nt = 0; nt < 3; ++nt) bc[nt] = bn[nt];
      }
    }
#pragma unroll
    for (int mt = 0; mt < 4; ++mt) {
#pragma unroll
      for (int nt = 0; nt < 3; ++nt) {
#pragma unroll
        for (int rg = 0; rg < 4; ++rg) {
          int row = mt * 16 + quad * 4 + rg;
          if (row < 49) {
            int n = wave * 48 + nt * 16 + r16;
            int f = (n >> 6) * 384 + hp * 64 + (n & 63);
            qkvs[row * 192 + n] = f2bf(acc[mt][nt][rg] + qkv_b[f]);
          }
        }
      }
    }
    __syncthreads();

    // ---- key-split attention: wave = (head hh2, half) ----
    const int hh2  = wave >> 1;          // 0/1 within head pair
    const int half = wave & 1;           // key half
    const int head = hp * 2 + hh2;
    float mx = -3.0e38f, den = 0.f, o[32];
#pragma unroll
    for (int k = 0; k < 32; ++k) o[k] = 0.f;

    if (lane < 49) {
      const int m0 = half ? 25 : 0, m1 = half ? 49 : 25;
      float q[32];
#pragma unroll
      for (int kk = 0; kk < 4; ++kk)
        unpack8(*(uint4*)&qkvs[lane * 192 + hh2 * 32 + kk * 8], q + kk * 8);
#pragma unroll
      for (int k = 0; k < 32; ++k) q[k] *= 0.17677669529663689f;

      // prologue: k-row m0 + bias m0
      float kr[32];
#pragma unroll
      for (int kk = 0; kk < 4; ++kk)
        unpack8(*(uint4*)&qkvs[m0 * 192 + 64 + hh2 * 32 + kk * 8], kr + kk * 8);
      int i2 = m0 / 7, j2 = m0 - (m0 / 7) * 7;
      float bias = btab[((i1 - i2 + 6) * 13 + (j1 - j2 + 6)) * 12 + head];

      for (int m = m0; m < m1; ++m) {
        // issue next k-row + next bias early (hidden under dot/exp)
        uint4 kn[4]; float bias_n = 0.f; int i2n = i2, j2n = j2;
        if (m + 1 < m1) {
#pragma unroll
          for (int kk = 0; kk < 4; ++kk)
            kn[kk] = *(uint4*)&qkvs[(m + 1) * 192 + 64 + hh2 * 32 + kk * 8];
          i2n = (m + 1) / 7; j2n = (m + 1) - i2n * 7;
          bias_n = btab[((i1 - i2n + 6) * 13 + (j1 - j2n + 6)) * 12 + head];
        }
        float d = 0.f;
#pragma unroll
        for (int k = 0; k < 32; ++k) d += q[k] * kr[k];
        d += bias;
        if (region3(wwh * 7 + i2) * 3 + region3(www * 7 + j2) != rid1) d -= 100.f;
        float vv[32];
#pragma unroll
        for (int kk = 0; kk < 4; ++kk)
          unpack8(*(uint4*)&qkvs[m * 192 + 128 + hh2 * 32 + kk * 8], vv + kk * 8);
        float nm = fmaxf(mx, d);
        float sc = __expf(mx - nm);
        float p  = __expf(d - nm);
        den = den * sc + p;
#pragma unroll
        for (int k = 0; k < 32; ++k) o[k] = o[k] * sc + p * vv[k];
        mx = nm;
        if (m + 1 < m1) {
#pragma unroll
          for (int kk = 0; kk < 4; ++kk) unpack8(kn[kk], kr + kk * 8);
          bias = bias_n; i2 = i2n; j2 = j2n;
        }
      }
      if (half) {   // upper half publishes its partial
#pragma unroll
        for (int k = 0; k < 32; ++k) po[hh2][lane][k] = f2bf(o[k]);
        pm[hh2][lane * 2] = mx; pm[hh2][lane * 2 + 1] = den;
      }
    }
    __syncthreads();

    // lower-half waves merge and write out
    if (!half && lane < 49) {
      float mx1  = pm[hh2][lane * 2];
      float den1 = pm[hh2][lane * 2 + 1];
      float nm = fmaxf(mx, mx1);
      float s0 = __expf(mx - nm), s1 = __expf(mx1 - nm);
      float inv = 1.f / (den * s0 + den1 * s1);
      int h  = wwh * 7 + i1 + 3; if (h  >= 28) h  -= 28;
      int w2 = www * 7 + j1 + 3; if (w2 >= 28) w2 -= 28;
      float* orow = out + ((size_t)(bimg * 784 + h * 28 + w2)) * 384 + head * 32;
#pragma unroll
      for (int k = 0; k < 8; ++k) {
        float4 f4;
        f4.x = (o[4*k]   * s0 + bf2f(po[hh2][lane][4*k])   * s1) * inv;
        f4.y = (o[4*k+1] * s0 + bf2f(po[hh2][lane][4*k+1]) * s1) * inv;
        f4.z = (o[4*k+2] * s0 + bf2f(po[hh2][lane][4*k+2]) * s1) * inv;
        f4.w = (o[4*k+3] * s0 + bf2f(po[hh2][lane][4*k+3]) * s1) * inv;
        *(float4*)&orow[4 * k] = f4;
      }
    }
    __syncthreads();
  }
}

// ---------------------------------------------------------------------------
// K2: proj + residual(x), in-place on d_out (fp32). 64 rows/block.
// ---------------------------------------------------------------------------
template<bool BF>
__global__ __launch_bounds__(256, 3) void proj_kernel(
    const float* attn, const void* __restrict__ proj_w, const float* __restrict__ proj_b,
    const float* __restrict__ x, float* outp)
{
  __shared__ __align__(16) u16 As[64 * 392];
  const int tid  = threadIdx.x;
  const int lane = tid & 63;
  const int wave = tid >> 6;
  const int quad = lane >> 4;
  const int r16  = lane & 15;
  const int bm   = blockIdx.x * 64;

  for (int e = tid * 8; e < 64 * 384; e += 2048) {
    int r = e / 384, c = e - (e / 384) * 384;
    *(uint4*)&As[r * 392 + c] = pack8f(attn + (size_t)(bm + r) * 384 + c);
  }
  __syncthreads();

  f32x4 acc[4][6];
#pragma unroll
  for (int a = 0; a < 4; ++a)
#pragma unroll
    for (int c = 0; c < 6; ++c) acc[a][c] = (f32x4){0.f, 0.f, 0.f, 0.f};

  auto loadB = [&](int nt, int kt) -> bf16x8 {
    if constexpr (BF) {
      return *(const bf16x8*)((const u16*)proj_w +
             ((((size_t)(wave * 6 + nt)) * 12 + kt) << 9) + r16 * 32 + quad * 8);
    } else {
      int n = wave * 96 + nt * 16 + r16;
      return ldw8((const float*)proj_w + (size_t)n * 384 + kt * 32 + quad * 8);
    }
  };

  bf16x8 bc[6];
#pragma unroll
  for (int nt = 0; nt < 6; ++nt) bc[nt] = loadB(nt, 0);
  for (int kt = 0; kt < 12; ++kt) {
    bf16x8 bn[6];
    if (kt < 11) {
#pragma unroll
      for (int nt = 0; nt < 6; ++nt) bn[nt] = loadB(nt, kt + 1);
    }
    bf16x8 af[4];
#pragma unroll
    for (int mt = 0; mt < 4; ++mt)
      af[mt] = *(const bf16x8*)&As[(mt * 16 + r16) * 392 + kt * 32 + quad * 8];
#pragma unroll
    for (int nt = 0; nt < 6; ++nt)
#pragma unroll
      for (int mt = 0; mt < 4; ++mt)
        acc[mt][nt] = __builtin_amdgcn_mfma_f32_16x16x32_bf16(af[mt], bc[nt], acc[mt][nt], 0, 0, 0);
    if (kt < 11) {
#pragma unroll
      for (int nt = 0; nt < 6; ++nt) bc[nt] = bn[nt];
    }
  }
#pragma unroll
  for (int mt = 0; mt < 4; ++mt) {
#pragma unroll
    for (int nt = 0; nt < 6; ++nt) {
#pragma unroll
      for (int rg = 0; rg < 4; ++rg) {
        int gm = bm + mt * 16 + quad * 4 + rg;
        int gn = wave * 96 + nt * 16 + r16;
        float v = acc[mt][nt][rg] + proj_b[gn] + x[(size_t)gm * 384 + gn];
        outp[(size_t)gm * 384 + gn] = v;
      }
    }
  }
}

// ---------------------------------------------------------------------------
// K3: fused LN2 + FC1 + GELU + FC2 + residual, M=64 rows/block.
// Hidden chunked 8x192: LDS = xs 50K + hs 25.6K -> 2 blocks/CU.
// ---------------------------------------------------------------------------
template<bool BF>
__global__ __launch_bounds__(256, 2) void mlp_kernel(
    const float* __restrict__ n2w, const float* __restrict__ n2b,
    const void* __restrict__ fc1_w, const float* __restrict__ fc1_b,
    const void* __restrict__ fc2_w, const float* __restrict__ fc2_b,
    float* xr)
{
  __shared__ __align__(16) u16 xs[64 * 392];   // 50,176 B
  __shared__ __align__(16) u16 hs[64 * 200];   // 25,600 B (one 192-col hidden chunk)
  __shared__ float mustd[128];
  const int tid  = threadIdx.x;
  const int lane = tid & 63;
  const int wave = tid >> 6;
  const int quad = lane >> 4;
  const int r16  = lane & 15;
  const int bm   = blockIdx.x * 64;

  for (int e = tid * 8; e < 64 * 384; e += 2048) {
    int r = e / 384, c = e - (e / 384) * 384;
    *(uint4*)&xs[r * 392 + c] = pack8f(xr + (size_t)(bm + r) * 384 + c);
  }
  __syncthreads();

  for (int r = wave; r < 64; r += 4) {
    float v[6]; float s = 0.f;
#pragma unroll
    for (int k = 0; k < 6; ++k) { v[k] = bf2f(xs[r * 392 + lane + k * 64]); s += v[k]; }
#pragma unroll
    for (int off = 32; off; off >>= 1) s += __shfl_xor(s, off);
    float mu = s * (1.f / 384.f);
    float vs = 0.f;
#pragma unroll
    for (int k = 0; k < 6; ++k) { float d = v[k] - mu; vs += d * d; }
#pragma unroll
    for (int off = 32; off; off >>= 1) vs += __shfl_xor(vs, off);
    if (lane == 0) { mustd[r] = mu; mustd[64 + r] = rsqrtf(vs * (1.f / 384.f) + 1e-5f); }
  }
  __syncthreads();

  for (int e = tid * 8; e < 64 * 384; e += 2048) {
    int r = e / 384, c = e - (e / 384) * 384;
    float mu = mustd[r], rs = mustd[64 + r];
    float v[8];
    unpack8(*(uint4*)&xs[r * 392 + c], v);
    float4 w0 = *(const float4*)(n2w + c), w1 = *(const float4*)(n2w + c + 4);
    float4 b0 = *(const float4*)(n2b + c), b1 = *(const float4*)(n2b + c + 4);
    float wv[8] = {w0.x, w0.y, w0.z, w0.w, w1.x, w1.y, w1.z, w1.w};
    float bv[8] = {b0.x, b0.y, b0.z, b0.w, b1.x, b1.y, b1.z, b1.w};
    unsigned pk[4];
#pragma unroll
    for (int i = 0; i < 4; ++i) {
      u16 a = f2bf((v[2*i]   - mu) * rs * wv[2*i]   + bv[2*i]);
      u16 b = f2bf((v[2*i+1] - mu) * rs * wv[2*i+1] + bv[2*i+1]);
      pk[i] = (unsigned)a | ((unsigned)b << 16);
    }
    *(uint4*)&xs[r * 392 + c] = make_uint4(pk[0], pk[1], pk[2], pk[3]);
  }
  __syncthreads();

  // FC2 accumulators persist across hidden chunks
  f32x4 acc2[4][6];
#pragma unroll
  for (int a = 0; a < 4; ++a)
#pragma unroll
    for (int c = 0; c < 6; ++c) acc2[a][c] = (f32x4){0.f, 0.f, 0.f, 0.f};

  for (int hc = 0; hc < 8; ++hc) {
    // --- FC1 chunk: 64 rows x 192 hidden cols (wave owns 48 cols = 3 nt) ---
    f32x4 acc1[4][3];
#pragma unroll
    for (int a = 0; a < 4; ++a)
#pragma unroll
      for (int c = 0; c < 3; ++c) acc1[a][c] = (f32x4){0.f, 0.f, 0.f, 0.f};

    auto loadB1 = [&](int nt, int kt) -> bf16x8 {
      if constexpr (BF) {
        int rt = hc * 12 + wave * 3 + nt;
        return *(const bf16x8*)((const u16*)fc1_w +
               ((((size_t)rt) * 12 + kt) << 9) + r16 * 32 + quad * 8);
      } else {
        int ng = hc * 192 + wave * 48 + nt * 16 + r16;
        return ldw8((const float*)fc1_w + (size_t)ng * 384 + kt * 32 + quad * 8);
      }
    };
    {
      bf16x8 bc[3];
#pragma unroll
      for (int nt = 0; nt < 3; ++nt) bc[nt] = loadB1(nt, 0);
      for (int kt = 0; kt < 12; ++kt) {
        bf16x8 bn[3];
        if (kt < 11) {
#pragma unroll
          for (int nt = 0; nt < 3; ++nt) bn[nt] = loadB1(nt, kt + 1);
        }
        bf16x8 af[4];
#pragma unroll
        for (int mt = 0; mt < 4; ++mt)
          af[mt] = *(const bf16x8*)&xs[(mt * 16 + r16) * 392 + kt * 32 + quad * 8];
#pragma unroll
        for (int nt = 0; nt < 3; ++nt)
#pragma unroll
          for (int mt = 0; mt < 4; ++mt)
            acc1[mt][nt] = __builtin_amdgcn_mfma_f32_16x16x32_bf16(af[mt], bc[nt], acc1[mt][nt], 0, 0, 0);
        if (kt < 11) {
#pragma unroll
          for (int nt = 0; nt < 3; ++nt) bc[nt] = bn[nt];
        }
      }
    }
    __syncthreads();   // prev chunk's FC2 reads of hs complete
    // --- GELU -> hs ---
#pragma unroll
    for (int mt = 0; mt < 4; ++mt) {
#pragma unroll
      for (int nt = 0; nt < 3; ++nt) {
#pragma unroll
        for (int rg = 0; rg < 4; ++rg) {
          int row = mt * 16 + quad * 4 + rg;
          int nl  = wave * 48 + nt * 16 + r16;
          float v = acc1[mt][nt][rg] + fc1_b[hc * 192 + nl];
          hs[row * 200 + nl] = f2bf(gelu_f(v));
        }
      }
    }
    __syncthreads();
    // --- FC2 partial over this chunk (k = 192, 6 k-steps) ---
    auto loadB2 = [&](int nt, int kk) -> bf16x8 {
      if constexpr (BF) {
        int rt = wave * 6 + nt;
        return *(const bf16x8*)((const u16*)fc2_w +
               ((((size_t)rt) * 48 + hc * 6 + kk) << 9) + r16 * 32 + quad * 8);
      } else {
        int n = wave * 96 + nt * 16 + r16;
        return ldw8((const float*)fc2_w + (size_t)n * 1536 + hc * 192 + kk * 32 + quad * 8);
      }
    };
    {
      bf16x8 bc[6];
#pragma unroll
      for (int nt = 0; nt < 6; ++nt) bc[nt] = loadB2(nt, 0);
      for (int kk = 0; kk < 6; ++kk) {
        bf16x8 bn[6];
        if (kk < 5) {
#pragma unroll
          for (int nt = 0; nt < 6; ++nt) bn[nt] = loadB2(nt, kk + 1);
        }
        bf16x8 af[4];
#pragma unroll
        for (int mt = 0; mt < 4; ++mt)
          af[mt] = *(const bf16x8*)&hs[(mt * 16 + r16) * 200 + kk * 32 + quad * 8];
#pragma unroll
        for (int nt = 0; nt < 6; ++nt)
#pragma unroll
          for (int mt = 0; mt < 4; ++mt)
            acc2[mt][nt] = __builtin_amdgcn_mfma_f32_16x16x32_bf16(af[mt], bc[nt], acc2[mt][nt], 0, 0, 0);
        if (kk < 5) {
#pragma unroll
          for (int nt = 0; nt < 6; ++nt) bc[nt] = bn[nt];
        }
      }
    }
  }

  // FC2 bias + residual (in-place, fp32)
#pragma unroll
  for (int mt = 0; mt < 4; ++mt) {
#pragma unroll
    for (int nt = 0; nt < 6; ++nt) {
#pragma unroll
      for (int rg = 0; rg < 4; ++rg) {
        int gm = bm + mt * 16 + quad * 4 + rg;
        int gn = wave * 96 + nt * 16 + r16;
        size_t g = (size_t)gm * 384 + gn;
        xr[g] = acc2[mt][nt][rg] + fc2_b[gn] + xr[g];
      }
    }
  }
}

// ---------------------------------------------------------------------------
extern "C" void kernel_launch(void* const* d_in, const int* in_sizes, int n_in,
                              void* d_out, int out_size, void* d_ws, size_t ws_size,
                              hipStream_t stream) {
  const float* x      = (const float*)d_in[0];
  const float* n1w    = (const float*)d_in[1];
  const float* n1b    = (const float*)d_in[2];
  const float* qkv_w  = (const float*)d_in[3];
  const float* qkv_b  = (const float*)d_in[4];
  const float* proj_w = (const float*)d_in[5];
  const float* proj_b = (const float*)d_in[6];
  const float* btab   = (const float*)d_in[7];
  const float* n2w    = (const float*)d_in[8];
  const float* n2b    = (const float*)d_in[9];
  const float* fc1_w  = (const float*)d_in[10];
  const float* fc1_b  = (const float*)d_in[11];
  const float* fc2_w  = (const float*)d_in[12];
  const float* fc2_b  = (const float*)d_in[13];

  float* dout = (float*)d_out;
  (void)in_sizes; (void)n_in; (void)out_size;

  const size_t NQ = 442368, NP = 147456, N1 = 589824, N2 = 589824;
  const size_t need = (NQ + NP + N1 + N2) * sizeof(u16);   // 3,538,944 B

  if (d_ws && ws_size >= need) {
    u16* wq = (u16*)d_ws;
    u16* wp = wq + NQ;
    u16* w1 = wp + NP;
    u16* w2 = w1 + N1;
    repack_kernel<<<(int)((NQ / 8 + 255) / 256), 256, 0, stream>>>(qkv_w,  wq, 1152, 384);
    repack_kernel<<<(int)((NP / 8 + 255) / 256), 256, 0, stream>>>(proj_w, wp, 384, 384);
    repack_kernel<<<(int)((N1 / 8 + 255) / 256), 256, 0, stream>>>(fc1_w,  w1, 1536, 384);
    repack_kernel<<<(int)((N2 / 8 + 255) / 256), 256, 0, stream>>>(fc2_w,  w2, 384, 1536);

    win_attn_kernel<true><<<1024, 256, 0, stream>>>(x, n1w, n1b, wq, qkv_b, btab, dout);
    proj_kernel<true><<<784, 256, 0, stream>>>(dout, wp, proj_b, x, dout);
    mlp_kernel<true><<<784, 256, 0, stream>>>(n2w, n2b, w1, fc1_b, w2, fc2_b, dout);
  } else {
    win_attn_kernel<false><<<1024, 256, 0, stream>>>(x, n1w, n1b, qkv_w, qkv_b, btab, dout);
    proj_kernel<false><<<784, 256, 0, stream>>>(dout, proj_w, proj_b, x, dout);
    mlp_kernel<false><<<784, 256, 0, stream>>>(n2w, n2b, fc1_w, fc1_b, fc2_w, fc2_b, dout);
  }
}

// Round 8
// 682.595 us; speedup vs baseline: 1.3633x; 1.2097x over previous
//
#include <hip/hip_runtime.h>

// ---------------------------------------------------------------------------
// Swin block, MI355X. ALL I/O fp32 (per reference); bf16 MFMA compute inside.
//   W0: weights fp32 -> bf16 TILED [R/16][K/32][16][32] into d_ws (guarded).
//   K1: fused LN1+shift+QKV (6 phases x 2 heads) + MFMA attention:
//       QK^T via MFMA (K rows as B-frags), shfl softmax, P->LDS (aliases QK
//       buffer behind a convergent barrier), PV via MFMA with V^T buffer.
//       LDS 79,752 B -> 2 blocks/CU.
//   K2: proj + residual, 64 rows/block, B-prefetch rotation.
//   K3: M=64 rows/block, hidden chunked 8x192, B-prefetch, 76KB LDS.
// B=64 H=W=28 DIM=384 HEADS=12 HD=32 WIN=7 SHIFT=3 N=49 NW=16 HID=1536
// ---------------------------------------------------------------------------

using u16 = unsigned short;
typedef __bf16 bf16x8 __attribute__((ext_vector_type(8)));
typedef float  f32x4  __attribute__((ext_vector_type(4)));

__device__ __forceinline__ float bf2f(u16 u) {
  unsigned x = ((unsigned)u) << 16; return __builtin_bit_cast(float, x);
}
__device__ __forceinline__ u16 f2bf(float f) {
  unsigned x = __builtin_bit_cast(unsigned, f);
  x += 0x7fffu + ((x >> 16) & 1u);   // RNE
  return (u16)(x >> 16);
}
__device__ __forceinline__ int region3(int s) { return s < 21 ? 0 : (s < 25 ? 1 : 2); }
__device__ __forceinline__ void unpack8(uint4 u, float* d) {
  d[0] = bf2f(u.x & 0xffff); d[1] = bf2f(u.x >> 16);
  d[2] = bf2f(u.y & 0xffff); d[3] = bf2f(u.y >> 16);
  d[4] = bf2f(u.z & 0xffff); d[5] = bf2f(u.z >> 16);
  d[6] = bf2f(u.w & 0xffff); d[7] = bf2f(u.w >> 16);
}
__device__ __forceinline__ uint4 pack8f(const float* p) {
  float4 a = *(const float4*)p, b = *(const float4*)(p + 4);
  uint4 u;
  u.x = (unsigned)f2bf(a.x) | ((unsigned)f2bf(a.y) << 16);
  u.y = (unsigned)f2bf(a.z) | ((unsigned)f2bf(a.w) << 16);
  u.z = (unsigned)f2bf(b.x) | ((unsigned)f2bf(b.y) << 16);
  u.w = (unsigned)f2bf(b.z) | ((unsigned)f2bf(b.w) << 16);
  return u;
}
// 8 consecutive fp32 -> bf16x8 MFMA fragment (fallback path only)
__device__ __forceinline__ bf16x8 ldw8(const float* p) {
  float4 a = *(const float4*)p, b = *(const float4*)(p + 4);
  bf16x8 r;
  r[0] = __builtin_bit_cast(__bf16, f2bf(a.x));
  r[1] = __builtin_bit_cast(__bf16, f2bf(a.y));
  r[2] = __builtin_bit_cast(__bf16, f2bf(a.z));
  r[3] = __builtin_bit_cast(__bf16, f2bf(a.w));
  r[4] = __builtin_bit_cast(__bf16, f2bf(b.x));
  r[5] = __builtin_bit_cast(__bf16, f2bf(b.y));
  r[6] = __builtin_bit_cast(__bf16, f2bf(b.z));
  r[7] = __builtin_bit_cast(__bf16, f2bf(b.w));
  return r;
}
// tanh-form GELU
__device__ __forceinline__ float gelu_f(float v) {
  float u = v * (0.7978845608028654f + 0.0356774081f * v * v);
  float e = __expf(2.f * u);
  float t = 1.f - 2.f / (e + 1.f);
  return 0.5f * v * (1.f + t);
}

// ---------------------------------------------------------------------------
// W0: fp32 [R][K] row-major -> bf16 tiled [R/16][K/32][16][32]
// ---------------------------------------------------------------------------
__global__ __launch_bounds__(256) void repack_kernel(
    const float* __restrict__ src, u16* __restrict__ dst, int R, int K)
{
  int i = blockIdx.x * 256 + threadIdx.x;
  int n8 = (R * K) >> 3;
  if (i >= n8) return;
  int e = i * 8;
  int r = e / K, c = e - (e / K) * K;
  size_t off = ((((size_t)(r >> 4)) * (K >> 5) + (c >> 5)) << 9) + (r & 15) * 32 + (c & 31);
  *(uint4*)&dst[off] = pack8f(src + (size_t)r * K + c);
}

// ---------------------------------------------------------------------------
// K1: per-window fused LN1 + QKV + MFMA attention.
// 6 phases x 2 heads; wave = (head wave>>1, row-half wave&1).
// LDS: xin 50,176 + uni 19,456 (QK [64][140] bf16, aliased by P [2][64][76])
//      + vt 9,728 ([2][32][76] V^T bf16) + mustd 392 = 79,752 B -> 2 blk/CU.
// ---------------------------------------------------------------------------
template<bool BF>
__global__ __launch_bounds__(256, 2) void win_attn_kernel(
    const float* __restrict__ x, const float* __restrict__ n1w, const float* __restrict__ n1b,
    const void* __restrict__ qkv_w, const float* __restrict__ qkv_b,
    const float* __restrict__ btab, float* __restrict__ out)
{
  __shared__ __align__(16) u16 xin[64 * 392];  // 50,176 B
  __shared__ __align__(16) u16 uni[9728];      // 19,456 B: QK[64][140] / P[2][64][76]
  __shared__ __align__(16) u16 vt[4864];       //  9,728 B: [2][32][76] V^T
  __shared__ float mustd[98];

  const int tid  = threadIdx.x;
  const int lane = tid & 63;
  const int wave = tid >> 6;
  const int quad = lane >> 4;
  const int r16  = lane & 15;

  const int win  = blockIdx.x;
  const int bimg = win >> 4;
  const int wi   = win & 15;
  const int wwh  = wi >> 2, www = wi & 3;

  // zero pads: xin rows 49..63, uni + vt entirely
  for (int e = tid * 8; e < 15 * 392; e += 2048)
    *(uint4*)&xin[49 * 392 + e] = make_uint4(0, 0, 0, 0);
  for (int e = tid * 8; e < 9728; e += 2048)
    *(uint4*)&uni[e] = make_uint4(0, 0, 0, 0);
  for (int e = tid * 8; e < 4864; e += 2048)
    *(uint4*)&vt[e] = make_uint4(0, 0, 0, 0);

  for (int e = tid * 8; e < 49 * 384; e += 2048) {
    int r = e / 384, c = e - (e / 384) * 384;
    int i = r / 7, j = r - (r / 7) * 7;
    int h  = wwh * 7 + i + 3; if (h  >= 28) h  -= 28;
    int w2 = www * 7 + j + 3; if (w2 >= 28) w2 -= 28;
    *(uint4*)&xin[r * 392 + c] =
        pack8f(x + ((size_t)(bimg * 784 + h * 28 + w2)) * 384 + c);
  }
  __syncthreads();

  for (int r = wave; r < 49; r += 4) {
    float v[6]; float s = 0.f;
#pragma unroll
    for (int k = 0; k < 6; ++k) { v[k] = bf2f(xin[r * 392 + lane + k * 64]); s += v[k]; }
#pragma unroll
    for (int off = 32; off; off >>= 1) s += __shfl_xor(s, off);
    float mu = s * (1.f / 384.f);
    float vs = 0.f;
#pragma unroll
    for (int k = 0; k < 6; ++k) { float d = v[k] - mu; vs += d * d; }
#pragma unroll
    for (int off = 32; off; off >>= 1) vs += __shfl_xor(vs, off);
    if (lane == 0) { mustd[r] = mu; mustd[49 + r] = rsqrtf(vs * (1.f / 384.f) + 1e-5f); }
  }
  __syncthreads();

  for (int e = tid * 8; e < 49 * 384; e += 2048) {
    int r = e / 384, c = e - (e / 384) * 384;
    float mu = mustd[r], rs = mustd[49 + r];
    float v[8];
    unpack8(*(uint4*)&xin[r * 392 + c], v);
    float4 w0 = *(const float4*)(n1w + c), w1 = *(const float4*)(n1w + c + 4);
    float4 b0 = *(const float4*)(n1b + c), b1 = *(const float4*)(n1b + c + 4);
    float wv[8] = {w0.x, w0.y, w0.z, w0.w, w1.x, w1.y, w1.z, w1.w};
    float bv[8] = {b0.x, b0.y, b0.z, b0.w, b1.x, b1.y, b1.z, b1.w};
    unsigned pk[4];
#pragma unroll
    for (int i = 0; i < 4; ++i) {
      u16 a = f2bf((v[2*i]   - mu) * rs * wv[2*i]   + bv[2*i]);
      u16 b = f2bf((v[2*i+1] - mu) * rs * wv[2*i+1] + bv[2*i+1]);
      pk[i] = (unsigned)a | ((unsigned)b << 16);
    }
    *(uint4*)&xin[r * 392 + c] = make_uint4(pk[0], pk[1], pk[2], pk[3]);
  }
  __syncthreads();

  for (int hp = 0; hp < 6; ++hp) {
    // ---- Phase A: QKV GEMM for 2 heads (N=192), B-prefetch rotation ----
    f32x4 acc[4][3];
#pragma unroll
    for (int a = 0; a < 4; ++a)
#pragma unroll
      for (int c = 0; c < 3; ++c) acc[a][c] = (f32x4){0.f, 0.f, 0.f, 0.f};

    auto loadB = [&](int nt, int kt) -> bf16x8 {
      if constexpr (BF) {
        int n_noR = wave * 48 + nt * 16;
        int ftile = (n_noR >> 6) * 24 + hp * 4 + ((n_noR >> 4) & 3);
        return *(const bf16x8*)((const u16*)qkv_w +
               ((((size_t)ftile) * 12 + kt) << 9) + r16 * 32 + quad * 8);
      } else {
        int n = wave * 48 + nt * 16 + r16;
        int f = (n >> 6) * 384 + hp * 64 + (n & 63);
        return ldw8((const float*)qkv_w + (size_t)f * 384 + kt * 32 + quad * 8);
      }
    };

    bf16x8 bc[3];
#pragma unroll
    for (int nt = 0; nt < 3; ++nt) bc[nt] = loadB(nt, 0);
    for (int kt = 0; kt < 12; ++kt) {
      bf16x8 bn[3];
      if (kt < 11) {
#pragma unroll
        for (int nt = 0; nt < 3; ++nt) bn[nt] = loadB(nt, kt + 1);
      }
      bf16x8 af[4];
#pragma unroll
      for (int mt = 0; mt < 4; ++mt)
        af[mt] = *(const bf16x8*)&xin[(mt * 16 + r16) * 392 + kt * 32 + quad * 8];
#pragma unroll
      for (int nt = 0; nt < 3; ++nt)
#pragma unroll
        for (int mt = 0; mt < 4; ++mt)
          acc[mt][nt] = __builtin_amdgcn_mfma_f32_16x16x32_bf16(af[mt], bc[nt], acc[mt][nt], 0, 0, 0);
      if (kt < 11) {
#pragma unroll
        for (int nt = 0; nt < 3; ++nt) bc[nt] = bn[nt];
      }
    }
    // epilogue: q|k -> uni[row][t*64+c6]; v -> vt[h2][d][row] (transposed)
#pragma unroll
    for (int mt = 0; mt < 4; ++mt) {
#pragma unroll
      for (int nt = 0; nt < 3; ++nt) {
#pragma unroll
        for (int rg = 0; rg < 4; ++rg) {
          int row = mt * 16 + quad * 4 + rg;
          if (row < 49) {
            int n = wave * 48 + nt * 16 + r16;
            int t = n >> 6, c6 = n & 63;
            float v = acc[mt][nt][rg] + qkv_b[t * 384 + hp * 64 + c6];
            if (t == 2) vt[(c6 >> 5) * 2432 + (c6 & 31) * 76 + row] = f2bf(v);
            else        uni[row * 140 + t * 64 + c6] = f2bf(v);
          }
        }
      }
    }
    // re-zero QK pad rows 49..63 (P writes dirtied them last phase)
    for (int e2 = tid * 4; e2 < 15 * 128; e2 += 1024) {
      int r = 49 + (e2 >> 7), c = e2 & 127;
      *(uint2*)&uni[r * 140 + c] = make_uint2(0, 0);
    }
    __syncthreads();

    // ---- Phase B: MFMA attention (wave = head h2, row-half) ----
    {
      const int h2   = wave >> 1;
      const int half = wave & 1;
      const int head = hp * 2 + h2;
      // QK^T: S = Q @ K^T (K rows as B-frags)
      f32x4 s[2][4];
#pragma unroll
      for (int a = 0; a < 2; ++a)
#pragma unroll
        for (int c = 0; c < 4; ++c) s[a][c] = (f32x4){0.f, 0.f, 0.f, 0.f};
      {
        bf16x8 aq[2], bk[4];
#pragma unroll
        for (int mt2 = 0; mt2 < 2; ++mt2)
          aq[mt2] = *(const bf16x8*)&uni[((half * 2 + mt2) * 16 + r16) * 140 + h2 * 32 + quad * 8];
#pragma unroll
        for (int nt = 0; nt < 4; ++nt)
          bk[nt] = *(const bf16x8*)&uni[(nt * 16 + r16) * 140 + 64 + h2 * 32 + quad * 8];
#pragma unroll
        for (int nt = 0; nt < 4; ++nt)
#pragma unroll
          for (int mt2 = 0; mt2 < 2; ++mt2)
            s[mt2][nt] = __builtin_amdgcn_mfma_f32_16x16x32_bf16(aq[mt2], bk[nt], s[mt2][nt], 0, 0, 0);
      }
      __syncthreads();   // all QK^T reads done before P overwrites uni

      // key-side geometry per nt (col = nt*16 + r16)
      int colv[4], rid2v[4], i2v[4], j2v[4];
#pragma unroll
      for (int nt = 0; nt < 4; ++nt) {
        int col = nt * 16 + r16; colv[nt] = col;
        int cc = col < 49 ? col : 48;
        int i2 = cc / 7, j2 = cc - i2 * 7;
        i2v[nt] = i2; j2v[nt] = j2;
        rid2v[nt] = region3(wwh * 7 + i2) * 3 + region3(www * 7 + j2);
      }
      float den[2][4];
      u16* pb = uni + h2 * 4864;   // P[64][76] for this head
#pragma unroll
      for (int mt2 = 0; mt2 < 2; ++mt2) {
#pragma unroll
        for (int rg = 0; rg < 4; ++rg) {
          int row = (half * 2 + mt2) * 16 + quad * 4 + rg;
          int rowc = row < 49 ? row : 48;
          int qi = rowc / 7, qj = rowc - qi * 7;
          int rid1 = region3(wwh * 7 + qi) * 3 + region3(www * 7 + qj);
          float v4[4];
#pragma unroll
          for (int nt = 0; nt < 4; ++nt) {
            if (colv[nt] < 49) {
              float sv = s[mt2][nt][rg] * 0.17677669529663689f;
              sv += btab[((qi - i2v[nt] + 6) * 13 + (qj - j2v[nt] + 6)) * 12 + head];
              if (rid2v[nt] != rid1) sv -= 100.f;
              v4[nt] = sv;
            } else v4[nt] = -1e30f;
          }
          float m = fmaxf(fmaxf(v4[0], v4[1]), fmaxf(v4[2], v4[3]));
#pragma unroll
          for (int off = 1; off < 16; off <<= 1) m = fmaxf(m, __shfl_xor(m, off));
          float p[4]; float sum = 0.f;
#pragma unroll
          for (int nt = 0; nt < 4; ++nt) { p[nt] = __expf(v4[nt] - m); sum += p[nt]; }
#pragma unroll
          for (int off = 1; off < 16; off <<= 1) sum += __shfl_xor(sum, off);
          den[mt2][rg] = sum;
#pragma unroll
          for (int nt = 0; nt < 4; ++nt)
            pb[row * 76 + nt * 16 + r16] = f2bf(p[nt]);
        }
      }
      // PV: O = P @ V (V^T rows contiguous in vt); reads own-wave P rows only
      f32x4 o[2][2];
#pragma unroll
      for (int a = 0; a < 2; ++a)
#pragma unroll
        for (int c = 0; c < 2; ++c) o[a][c] = (f32x4){0.f, 0.f, 0.f, 0.f};
#pragma unroll
      for (int kc = 0; kc < 2; ++kc) {
        bf16x8 ap[2], bv[2];
#pragma unroll
        for (int mt2 = 0; mt2 < 2; ++mt2)
          ap[mt2] = *(const bf16x8*)&pb[((half * 2 + mt2) * 16 + r16) * 76 + kc * 32 + quad * 8];
#pragma unroll
        for (int nt = 0; nt < 2; ++nt)
          bv[nt] = *(const bf16x8*)&vt[h2 * 2432 + (nt * 16 + r16) * 76 + kc * 32 + quad * 8];
#pragma unroll
        for (int nt = 0; nt < 2; ++nt)
#pragma unroll
          for (int mt2 = 0; mt2 < 2; ++mt2)
            o[mt2][nt] = __builtin_amdgcn_mfma_f32_16x16x32_bf16(ap[mt2], bv[nt], o[mt2][nt], 0, 0, 0);
      }
      // scatter O rows (pixel order) with /den
#pragma unroll
      for (int mt2 = 0; mt2 < 2; ++mt2) {
#pragma unroll
        for (int rg = 0; rg < 4; ++rg) {
          int row = (half * 2 + mt2) * 16 + quad * 4 + rg;
          if (row < 49) {
            float inv = 1.f / den[mt2][rg];
            int qi = row / 7, qj = row - qi * 7;
            int h  = wwh * 7 + qi + 3; if (h  >= 28) h  -= 28;
            int w2 = www * 7 + qj + 3; if (w2 >= 28) w2 -= 28;
            float* orow = out + ((size_t)(bimg * 784 + h * 28 + w2)) * 384 + head * 32;
#pragma unroll
            for (int nt = 0; nt < 2; ++nt)
              orow[nt * 16 + r16] = o[mt2][nt][rg] * inv;
          }
        }
      }
    }
    __syncthreads();
  }
}

// ---------------------------------------------------------------------------
// K2: proj + residual(x), in-place on d_out (fp32). 64 rows/block.
// ---------------------------------------------------------------------------
template<bool BF>
__global__ __launch_bounds__(256, 3) void proj_kernel(
    const float* attn, const void* __restrict__ proj_w, const float* __restrict__ proj_b,
    const float* __restrict__ x, float* outp)
{
  __shared__ __align__(16) u16 As[64 * 392];
  const int tid  = threadIdx.x;
  const int lane = tid & 63;
  const int wave = tid >> 6;
  const int quad = lane >> 4;
  const int r16  = lane & 15;
  const int bm   = blockIdx.x * 64;

  for (int e = tid * 8; e < 64 * 384; e += 2048) {
    int r = e / 384, c = e - (e / 384) * 384;
    *(uint4*)&As[r * 392 + c] = pack8f(attn + (size_t)(bm + r) * 384 + c);
  }
  __syncthreads();

  f32x4 acc[4][6];
#pragma unroll
  for (int a = 0; a < 4; ++a)
#pragma unroll
    for (int c = 0; c < 6; ++c) acc[a][c] = (f32x4){0.f, 0.f, 0.f, 0.f};

  auto loadB = [&](int nt, int kt) -> bf16x8 {
    if constexpr (BF) {
      return *(const bf16x8*)((const u16*)proj_w +
             ((((size_t)(wave * 6 + nt)) * 12 + kt) << 9) + r16 * 32 + quad * 8);
    } else {
      int n = wave * 96 + nt * 16 + r16;
      return ldw8((const float*)proj_w + (size_t)n * 384 + kt * 32 + quad * 8);
    }
  };

  bf16x8 bc[6];
#pragma unroll
  for (int nt = 0; nt < 6; ++nt) bc[nt] = loadB(nt, 0);
  for (int kt = 0; kt < 12; ++kt) {
    bf16x8 bn[6];
    if (kt < 11) {
#pragma unroll
      for (int nt = 0; nt < 6; ++nt) bn[nt] = loadB(nt, kt + 1);
    }
    bf16x8 af[4];
#pragma unroll
    for (int mt = 0; mt < 4; ++mt)
      af[mt] = *(const bf16x8*)&As[(mt * 16 + r16) * 392 + kt * 32 + quad * 8];
#pragma unroll
    for (int nt = 0; nt < 6; ++nt)
#pragma unroll
      for (int mt = 0; mt < 4; ++mt)
        acc[mt][nt] = __builtin_amdgcn_mfma_f32_16x16x32_bf16(af[mt], bc[nt], acc[mt][nt], 0, 0, 0);
    if (kt < 11) {
#pragma unroll
      for (int nt = 0; nt < 6; ++nt) bc[nt] = bn[nt];
    }
  }
#pragma unroll
  for (int mt = 0; mt < 4; ++mt) {
#pragma unroll
    for (int nt = 0; nt < 6; ++nt) {
#pragma unroll
      for (int rg = 0; rg < 4; ++rg) {
        int gm = bm + mt * 16 + quad * 4 + rg;
        int gn = wave * 96 + nt * 16 + r16;
        float v = acc[mt][nt][rg] + proj_b[gn] + x[(size_t)gm * 384 + gn];
        outp[(size_t)gm * 384 + gn] = v;
      }
    }
  }
}

// ---------------------------------------------------------------------------
// K3: fused LN2 + FC1 + GELU + FC2 + residual, M=64 rows/block.
// Hidden chunked 8x192: LDS = xs 50K + hs 25.6K -> 2 blocks/CU.
// ---------------------------------------------------------------------------
template<bool BF>
__global__ __launch_bounds__(256, 2) void mlp_kernel(
    const float* __restrict__ n2w, const float* __restrict__ n2b,
    const void* __restrict__ fc1_w, const float* __restrict__ fc1_b,
    const void* __restrict__ fc2_w, const float* __restrict__ fc2_b,
    float* xr)
{
  __shared__ __align__(16) u16 xs[64 * 392];   // 50,176 B
  __shared__ __align__(16) u16 hs[64 * 200];   // 25,600 B (one 192-col hidden chunk)
  __shared__ float mustd[128];
  const int tid  = threadIdx.x;
  const int lane = tid & 63;
  const int wave = tid >> 6;
  const int quad = lane >> 4;
  const int r16  = lane & 15;
  const int bm   = blockIdx.x * 64;

  for (int e = tid * 8; e < 64 * 384; e += 2048) {
    int r = e / 384, c = e - (e / 384) * 384;
    *(uint4*)&xs[r * 392 + c] = pack8f(xr + (size_t)(bm + r) * 384 + c);
  }
  __syncthreads();

  for (int r = wave; r < 64; r += 4) {
    float v[6]; float s = 0.f;
#pragma unroll
    for (int k = 0; k < 6; ++k) { v[k] = bf2f(xs[r * 392 + lane + k * 64]); s += v[k]; }
#pragma unroll
    for (int off = 32; off; off >>= 1) s += __shfl_xor(s, off);
    float mu = s * (1.f / 384.f);
    float vs = 0.f;
#pragma unroll
    for (int k = 0; k < 6; ++k) { float d = v[k] - mu; vs += d * d; }
#pragma unroll
    for (int off = 32; off; off >>= 1) vs += __shfl_xor(vs, off);
    if (lane == 0) { mustd[r] = mu; mustd[64 + r] = rsqrtf(vs * (1.f / 384.f) + 1e-5f); }
  }
  __syncthreads();

  for (int e = tid * 8; e < 64 * 384; e += 2048) {
    int r = e / 384, c = e - (e / 384) * 384;
    float mu = mustd[r], rs = mustd[64 + r];
    float v[8];
    unpack8(*(uint4*)&xs[r * 392 + c], v);
    float4 w0 = *(const float4*)(n2w + c), w1 = *(const float4*)(n2w + c + 4);
    float4 b0 = *(const float4*)(n2b + c), b1 = *(const float4*)(n2b + c + 4);
    float wv[8] = {w0.x, w0.y, w0.z, w0.w, w1.x, w1.y, w1.z, w1.w};
    float bv[8] = {b0.x, b0.y, b0.z, b0.w, b1.x, b1.y, b1.z, b1.w};
    unsigned pk[4];
#pragma unroll
    for (int i = 0; i < 4; ++i) {
      u16 a = f2bf((v[2*i]   - mu) * rs * wv[2*i]   + bv[2*i]);
      u16 b = f2bf((v[2*i+1] - mu) * rs * wv[2*i+1] + bv[2*i+1]);
      pk[i] = (unsigned)a | ((unsigned)b << 16);
    }
    *(uint4*)&xs[r * 392 + c] = make_uint4(pk[0], pk[1], pk[2], pk[3]);
  }
  __syncthreads();

  // FC2 accumulators persist across hidden chunks
  f32x4 acc2[4][6];
#pragma unroll
  for (int a = 0; a < 4; ++a)
#pragma unroll
    for (int c = 0; c < 6; ++c) acc2[a][c] = (f32x4){0.f, 0.f, 0.f, 0.f};

  for (int hc = 0; hc < 8; ++hc) {
    // --- FC1 chunk: 64 rows x 192 hidden cols (wave owns 48 cols = 3 nt) ---
    f32x4 acc1[4][3];
#pragma unroll
    for (int a = 0; a < 4; ++a)
#pragma unroll
      for (int c = 0; c < 3; ++c) acc1[a][c] = (f32x4){0.f, 0.f, 0.f, 0.f};

    auto loadB1 = [&](int nt, int kt) -> bf16x8 {
      if constexpr (BF) {
        int rt = hc * 12 + wave * 3 + nt;
        return *(const bf16x8*)((const u16*)fc1_w +
               ((((size_t)rt) * 12 + kt) << 9) + r16 * 32 + quad * 8);
      } else {
        int ng = hc * 192 + wave * 48 + nt * 16 + r16;
        return ldw8((const float*)fc1_w + (size_t)ng * 384 + kt * 32 + quad * 8);
      }
    };
    {
      bf16x8 bc[3];
#pragma unroll
      for (int nt = 0; nt < 3; ++nt) bc[nt] = loadB1(nt, 0);
      for (int kt = 0; kt < 12; ++kt) {
        bf16x8 bn[3];
        if (kt < 11) {
#pragma unroll
          for (int nt = 0; nt < 3; ++nt) bn[nt] = loadB1(nt, kt + 1);
        }
        bf16x8 af[4];
#pragma unroll
        for (int mt = 0; mt < 4; ++mt)
          af[mt] = *(const bf16x8*)&xs[(mt * 16 + r16) * 392 + kt * 32 + quad * 8];
#pragma unroll
        for (int nt = 0; nt < 3; ++nt)
#pragma unroll
          for (int mt = 0; mt < 4; ++mt)
            acc1[mt][nt] = __builtin_amdgcn_mfma_f32_16x16x32_bf16(af[mt], bc[nt], acc1[mt][nt], 0, 0, 0);
        if (kt < 11) {
#pragma unroll
          for (int nt = 0; nt < 3; ++nt) bc[nt] = bn[nt];
        }
      }
    }
    __syncthreads();   // prev chunk's FC2 reads of hs complete
    // --- GELU -> hs ---
#pragma unroll
    for (int mt = 0; mt < 4; ++mt) {
#pragma unroll
      for (int nt = 0; nt < 3; ++nt) {
#pragma unroll
        for (int rg = 0; rg < 4; ++rg) {
          int row = mt * 16 + quad * 4 + rg;
          int nl  = wave * 48 + nt * 16 + r16;
          float v = acc1[mt][nt][rg] + fc1_b[hc * 192 + nl];
          hs[row * 200 + nl] = f2bf(gelu_f(v));
        }
      }
    }
    __syncthreads();
    // --- FC2 partial over this chunk (k = 192, 6 k-steps) ---
    auto loadB2 = [&](int nt, int kk) -> bf16x8 {
      if constexpr (BF) {
        int rt = wave * 6 + nt;
        return *(const bf16x8*)((const u16*)fc2_w +
               ((((size_t)rt) * 48 + hc * 6 + kk) << 9) + r16 * 32 + quad * 8);
      } else {
        int n = wave * 96 + nt * 16 + r16;
        return ldw8((const float*)fc2_w + (size_t)n * 1536 + hc * 192 + kk * 32 + quad * 8);
      }
    };
    {
      bf16x8 bc[6];
#pragma unroll
      for (int nt = 0; nt < 6; ++nt) bc[nt] = loadB2(nt, 0);
      for (int kk = 0; kk < 6; ++kk) {
        bf16x8 bn[6];
        if (kk < 5) {
#pragma unroll
          for (int nt = 0; nt < 6; ++nt) bn[nt] = loadB2(nt, kk + 1);
        }
        bf16x8 af[4];
#pragma unroll
        for (int mt = 0; mt < 4; ++mt)
          af[mt] = *(const bf16x8*)&hs[(mt * 16 + r16) * 200 + kk * 32 + quad * 8];
#pragma unroll
        for (int nt = 0; nt < 6; ++nt)
#pragma unroll
          for (int mt = 0; mt < 4; ++mt)
            acc2[mt][nt] = __builtin_amdgcn_mfma_f32_16x16x32_bf16(af[mt], bc[nt], acc2[mt][nt], 0, 0, 0);
        if (kk < 5) {
#pragma unroll
          for (int nt = 0; nt < 6; ++nt) bc[nt] = bn[nt];
        }
      }
    }
  }

  // FC2 bias + residual (in-place, fp32)
#pragma unroll
  for (int mt = 0; mt < 4; ++mt) {
#pragma unroll
    for (int nt = 0; nt < 6; ++nt) {
#pragma unroll
      for (int rg = 0; rg < 4; ++rg) {
        int gm = bm + mt * 16 + quad * 4 + rg;
        int gn = wave * 96 + nt * 16 + r16;
        size_t g = (size_t)gm * 384 + gn;
        xr[g] = acc2[mt][nt][rg] + fc2_b[gn] + xr[g];
      }
    }
  }
}

// ---------------------------------------------------------------------------
extern "C" void kernel_launch(void* const* d_in, const int* in_sizes, int n_in,
                              void* d_out, int out_size, void* d_ws, size_t ws_size,
                              hipStream_t stream) {
  const float* x      = (const float*)d_in[0];
  const float* n1w    = (const float*)d_in[1];
  const float* n1b    = (const float*)d_in[2];
  const float* qkv_w  = (const float*)d_in[3];
  const float* qkv_b  = (const float*)d_in[4];
  const float* proj_w = (const float*)d_in[5];
  const float* proj_b = (const float*)d_in[6];
  const float* btab   = (const float*)d_in[7];
  const float* n2w    = (const float*)d_in[8];
  const float* n2b    = (const float*)d_in[9];
  const float* fc1_w  = (const float*)d_in[10];
  const float* fc1_b  = (const float*)d_in[11];
  const float* fc2_w  = (const float*)d_in[12];
  const float* fc2_b  = (const float*)d_in[13];

  float* dout = (float*)d_out;
  (void)in_sizes; (void)n_in; (void)out_size;

  const size_t NQ = 442368, NP = 147456, N1 = 589824, N2 = 589824;
  const size_t need = (NQ + NP + N1 + N2) * sizeof(u16);   // 3,538,944 B

  if (d_ws && ws_size >= need) {
    u16* wq = (u16*)d_ws;
    u16* wp = wq + NQ;
    u16* w1 = wp + NP;
    u16* w2 = w1 + N1;
    repack_kernel<<<(int)((NQ / 8 + 255) / 256), 256, 0, stream>>>(qkv_w,  wq, 1152, 384);
    repack_kernel<<<(int)((NP / 8 + 255) / 256), 256, 0, stream>>>(proj_w, wp, 384, 384);
    repack_kernel<<<(int)((N1 / 8 + 255) / 256), 256, 0, stream>>>(fc1_w,  w1, 1536, 384);
    repack_kernel<<<(int)((N2 / 8 + 255) / 256), 256, 0, stream>>>(fc2_w,  w2, 384, 1536);

    win_attn_kernel<true><<<1024, 256, 0, stream>>>(x, n1w, n1b, wq, qkv_b, btab, dout);
    proj_kernel<true><<<784, 256, 0, stream>>>(dout, wp, proj_b, x, dout);
    mlp_kernel<true><<<784, 256, 0, stream>>>(n2w, n2b, w1, fc1_b, w2, fc2_b, dout);
  } else {
    win_attn_kernel<false><<<1024, 256, 0, stream>>>(x, n1w, n1b, qkv_w, qkv_b, btab, dout);
    proj_kernel<false><<<784, 256, 0, stream>>>(dout, proj_w, proj_b, x, dout);
    mlp_kernel<false><<<784, 256, 0, stream>>>(n2w, n2b, fc1_w, fc1_b, fc2_w, fc2_b, dout);
  }
}

// Round 9
// 576.817 us; speedup vs baseline: 1.6133x; 1.1834x over previous
//
#include <hip/hip_runtime.h>

// ---------------------------------------------------------------------------
// Swin block, MI355X. ALL I/O fp32 (per reference); bf16 MFMA compute inside.
//   W0: weights fp32 -> bf16 TILED [R/16][K/32][16][32] into d_ws (guarded).
//   K1: fused LN1+shift+QKV (6 phases x 2 heads) + MFMA attention (proven).
//   K2+K3 FUSED (pm_kernel): proj GEMM initializes the FC2 accumulator
//       (identical fragment layout), + proj_b + x residual in registers;
//       xr never touches global. xs staged attn -> overwritten with bf16 xr
//       for LN2 behind a barrier. Then LN2+FC1+GELU+FC2 chunks as proven.
//       Final write: out = acc2 + fc2_b. Saves 150 MB HBM + one launch.
// B=64 H=W=28 DIM=384 HEADS=12 HD=32 WIN=7 SHIFT=3 N=49 NW=16 HID=1536
// ---------------------------------------------------------------------------

using u16 = unsigned short;
typedef __bf16 bf16x8 __attribute__((ext_vector_type(8)));
typedef float  f32x4  __attribute__((ext_vector_type(4)));

__device__ __forceinline__ float bf2f(u16 u) {
  unsigned x = ((unsigned)u) << 16; return __builtin_bit_cast(float, x);
}
__device__ __forceinline__ u16 f2bf(float f) {
  unsigned x = __builtin_bit_cast(unsigned, f);
  x += 0x7fffu + ((x >> 16) & 1u);   // RNE
  return (u16)(x >> 16);
}
__device__ __forceinline__ int region3(int s) { return s < 21 ? 0 : (s < 25 ? 1 : 2); }
__device__ __forceinline__ void unpack8(uint4 u, float* d) {
  d[0] = bf2f(u.x & 0xffff); d[1] = bf2f(u.x >> 16);
  d[2] = bf2f(u.y & 0xffff); d[3] = bf2f(u.y >> 16);
  d[4] = bf2f(u.z & 0xffff); d[5] = bf2f(u.z >> 16);
  d[6] = bf2f(u.w & 0xffff); d[7] = bf2f(u.w >> 16);
}
__device__ __forceinline__ uint4 pack8f(const float* p) {
  float4 a = *(const float4*)p, b = *(const float4*)(p + 4);
  uint4 u;
  u.x = (unsigned)f2bf(a.x) | ((unsigned)f2bf(a.y) << 16);
  u.y = (unsigned)f2bf(a.z) | ((unsigned)f2bf(a.w) << 16);
  u.z = (unsigned)f2bf(b.x) | ((unsigned)f2bf(b.y) << 16);
  u.w = (unsigned)f2bf(b.z) | ((unsigned)f2bf(b.w) << 16);
  return u;
}
// 8 consecutive fp32 -> bf16x8 MFMA fragment (fallback path only)
__device__ __forceinline__ bf16x8 ldw8(const float* p) {
  float4 a = *(const float4*)p, b = *(const float4*)(p + 4);
  bf16x8 r;
  r[0] = __builtin_bit_cast(__bf16, f2bf(a.x));
  r[1] = __builtin_bit_cast(__bf16, f2bf(a.y));
  r[2] = __builtin_bit_cast(__bf16, f2bf(a.z));
  r[3] = __builtin_bit_cast(__bf16, f2bf(a.w));
  r[4] = __builtin_bit_cast(__bf16, f2bf(b.x));
  r[5] = __builtin_bit_cast(__bf16, f2bf(b.y));
  r[6] = __builtin_bit_cast(__bf16, f2bf(b.z));
  r[7] = __builtin_bit_cast(__bf16, f2bf(b.w));
  return r;
}
// tanh-form GELU
__device__ __forceinline__ float gelu_f(float v) {
  float u = v * (0.7978845608028654f + 0.0356774081f * v * v);
  float e = __expf(2.f * u);
  float t = 1.f - 2.f / (e + 1.f);
  return 0.5f * v * (1.f + t);
}

// ---------------------------------------------------------------------------
// W0: fp32 [R][K] row-major -> bf16 tiled [R/16][K/32][16][32]
// ---------------------------------------------------------------------------
__global__ __launch_bounds__(256) void repack_kernel(
    const float* __restrict__ src, u16* __restrict__ dst, int R, int K)
{
  int i = blockIdx.x * 256 + threadIdx.x;
  int n8 = (R * K) >> 3;
  if (i >= n8) return;
  int e = i * 8;
  int r = e / K, c = e - (e / K) * K;
  size_t off = ((((size_t)(r >> 4)) * (K >> 5) + (c >> 5)) << 9) + (r & 15) * 32 + (c & 31);
  *(uint4*)&dst[off] = pack8f(src + (size_t)r * K + c);
}

// ---------------------------------------------------------------------------
// K1: per-window fused LN1 + QKV + MFMA attention.  (unchanged, proven)
// 6 phases x 2 heads; wave = (head wave>>1, row-half wave&1).
// LDS: xin 50,176 + uni 19,456 + vt 9,728 + mustd 392 = 79,752 B -> 2 blk/CU.
// ---------------------------------------------------------------------------
template<bool BF>
__global__ __launch_bounds__(256, 2) void win_attn_kernel(
    const float* __restrict__ x, const float* __restrict__ n1w, const float* __restrict__ n1b,
    const void* __restrict__ qkv_w, const float* __restrict__ qkv_b,
    const float* __restrict__ btab, float* __restrict__ out)
{
  __shared__ __align__(16) u16 xin[64 * 392];  // 50,176 B
  __shared__ __align__(16) u16 uni[9728];      // 19,456 B: QK[64][140] / P[2][64][76]
  __shared__ __align__(16) u16 vt[4864];       //  9,728 B: [2][32][76] V^T
  __shared__ float mustd[98];

  const int tid  = threadIdx.x;
  const int lane = tid & 63;
  const int wave = tid >> 6;
  const int quad = lane >> 4;
  const int r16  = lane & 15;

  const int win  = blockIdx.x;
  const int bimg = win >> 4;
  const int wi   = win & 15;
  const int wwh  = wi >> 2, www = wi & 3;

  for (int e = tid * 8; e < 15 * 392; e += 2048)
    *(uint4*)&xin[49 * 392 + e] = make_uint4(0, 0, 0, 0);
  for (int e = tid * 8; e < 9728; e += 2048)
    *(uint4*)&uni[e] = make_uint4(0, 0, 0, 0);
  for (int e = tid * 8; e < 4864; e += 2048)
    *(uint4*)&vt[e] = make_uint4(0, 0, 0, 0);

  for (int e = tid * 8; e < 49 * 384; e += 2048) {
    int r = e / 384, c = e - (e / 384) * 384;
    int i = r / 7, j = r - (r / 7) * 7;
    int h  = wwh * 7 + i + 3; if (h  >= 28) h  -= 28;
    int w2 = www * 7 + j + 3; if (w2 >= 28) w2 -= 28;
    *(uint4*)&xin[r * 392 + c] =
        pack8f(x + ((size_t)(bimg * 784 + h * 28 + w2)) * 384 + c);
  }
  __syncthreads();

  for (int r = wave; r < 49; r += 4) {
    float v[6]; float s = 0.f;
#pragma unroll
    for (int k = 0; k < 6; ++k) { v[k] = bf2f(xin[r * 392 + lane + k * 64]); s += v[k]; }
#pragma unroll
    for (int off = 32; off; off >>= 1) s += __shfl_xor(s, off);
    float mu = s * (1.f / 384.f);
    float vs = 0.f;
#pragma unroll
    for (int k = 0; k < 6; ++k) { float d = v[k] - mu; vs += d * d; }
#pragma unroll
    for (int off = 32; off; off >>= 1) vs += __shfl_xor(vs, off);
    if (lane == 0) { mustd[r] = mu; mustd[49 + r] = rsqrtf(vs * (1.f / 384.f) + 1e-5f); }
  }
  __syncthreads();

  for (int e = tid * 8; e < 49 * 384; e += 2048) {
    int r = e / 384, c = e - (e / 384) * 384;
    float mu = mustd[r], rs = mustd[49 + r];
    float v[8];
    unpack8(*(uint4*)&xin[r * 392 + c], v);
    float4 w0 = *(const float4*)(n1w + c), w1 = *(const float4*)(n1w + c + 4);
    float4 b0 = *(const float4*)(n1b + c), b1 = *(const float4*)(n1b + c + 4);
    float wv[8] = {w0.x, w0.y, w0.z, w0.w, w1.x, w1.y, w1.z, w1.w};
    float bv[8] = {b0.x, b0.y, b0.z, b0.w, b1.x, b1.y, b1.z, b1.w};
    unsigned pk[4];
#pragma unroll
    for (int i = 0; i < 4; ++i) {
      u16 a = f2bf((v[2*i]   - mu) * rs * wv[2*i]   + bv[2*i]);
      u16 b = f2bf((v[2*i+1] - mu) * rs * wv[2*i+1] + bv[2*i+1]);
      pk[i] = (unsigned)a | ((unsigned)b << 16);
    }
    *(uint4*)&xin[r * 392 + c] = make_uint4(pk[0], pk[1], pk[2], pk[3]);
  }
  __syncthreads();

  for (int hp = 0; hp < 6; ++hp) {
    // ---- Phase A: QKV GEMM for 2 heads (N=192), B-prefetch rotation ----
    f32x4 acc[4][3];
#pragma unroll
    for (int a = 0; a < 4; ++a)
#pragma unroll
      for (int c = 0; c < 3; ++c) acc[a][c] = (f32x4){0.f, 0.f, 0.f, 0.f};

    auto loadB = [&](int nt, int kt) -> bf16x8 {
      if constexpr (BF) {
        int n_noR = wave * 48 + nt * 16;
        int ftile = (n_noR >> 6) * 24 + hp * 4 + ((n_noR >> 4) & 3);
        return *(const bf16x8*)((const u16*)qkv_w +
               ((((size_t)ftile) * 12 + kt) << 9) + r16 * 32 + quad * 8);
      } else {
        int n = wave * 48 + nt * 16 + r16;
        int f = (n >> 6) * 384 + hp * 64 + (n & 63);
        return ldw8((const float*)qkv_w + (size_t)f * 384 + kt * 32 + quad * 8);
      }
    };

    bf16x8 bc[3];
#pragma unroll
    for (int nt = 0; nt < 3; ++nt) bc[nt] = loadB(nt, 0);
    for (int kt = 0; kt < 12; ++kt) {
      bf16x8 bn[3];
      if (kt < 11) {
#pragma unroll
        for (int nt = 0; nt < 3; ++nt) bn[nt] = loadB(nt, kt + 1);
      }
      bf16x8 af[4];
#pragma unroll
      for (int mt = 0; mt < 4; ++mt)
        af[mt] = *(const bf16x8*)&xin[(mt * 16 + r16) * 392 + kt * 32 + quad * 8];
#pragma unroll
      for (int nt = 0; nt < 3; ++nt)
#pragma unroll
        for (int mt = 0; mt < 4; ++mt)
          acc[mt][nt] = __builtin_amdgcn_mfma_f32_16x16x32_bf16(af[mt], bc[nt], acc[mt][nt], 0, 0, 0);
      if (kt < 11) {
#pragma unroll
        for (int nt = 0; nt < 3; ++nt) bc[nt] = bn[nt];
      }
    }
    // epilogue: q|k -> uni[row][t*64+c6]; v -> vt[h2][d][row] (transposed)
#pragma unroll
    for (int mt = 0; mt < 4; ++mt) {
#pragma unroll
      for (int nt = 0; nt < 3; ++nt) {
#pragma unroll
        for (int rg = 0; rg < 4; ++rg) {
          int row = mt * 16 + quad * 4 + rg;
          if (row < 49) {
            int n = wave * 48 + nt * 16 + r16;
            int t = n >> 6, c6 = n & 63;
            float v = acc[mt][nt][rg] + qkv_b[t * 384 + hp * 64 + c6];
            if (t == 2) vt[(c6 >> 5) * 2432 + (c6 & 31) * 76 + row] = f2bf(v);
            else        uni[row * 140 + t * 64 + c6] = f2bf(v);
          }
        }
      }
    }
    // re-zero QK pad rows 49..63 (P writes dirtied them last phase)
    for (int e2 = tid * 4; e2 < 15 * 128; e2 += 1024) {
      int r = 49 + (e2 >> 7), c = e2 & 127;
      *(uint2*)&uni[r * 140 + c] = make_uint2(0, 0);
    }
    __syncthreads();

    // ---- Phase B: MFMA attention (wave = head h2, row-half) ----
    {
      const int h2   = wave >> 1;
      const int half = wave & 1;
      const int head = hp * 2 + h2;
      f32x4 s[2][4];
#pragma unroll
      for (int a = 0; a < 2; ++a)
#pragma unroll
        for (int c = 0; c < 4; ++c) s[a][c] = (f32x4){0.f, 0.f, 0.f, 0.f};
      {
        bf16x8 aq[2], bk[4];
#pragma unroll
        for (int mt2 = 0; mt2 < 2; ++mt2)
          aq[mt2] = *(const bf16x8*)&uni[((half * 2 + mt2) * 16 + r16) * 140 + h2 * 32 + quad * 8];
#pragma unroll
        for (int nt = 0; nt < 4; ++nt)
          bk[nt] = *(const bf16x8*)&uni[(nt * 16 + r16) * 140 + 64 + h2 * 32 + quad * 8];
#pragma unroll
        for (int nt = 0; nt < 4; ++nt)
#pragma unroll
          for (int mt2 = 0; mt2 < 2; ++mt2)
            s[mt2][nt] = __builtin_amdgcn_mfma_f32_16x16x32_bf16(aq[mt2], bk[nt], s[mt2][nt], 0, 0, 0);
      }
      __syncthreads();   // all QK^T reads done before P overwrites uni

      int colv[4], rid2v[4], i2v[4], j2v[4];
#pragma unroll
      for (int nt = 0; nt < 4; ++nt) {
        int col = nt * 16 + r16; colv[nt] = col;
        int cc = col < 49 ? col : 48;
        int i2 = cc / 7, j2 = cc - i2 * 7;
        i2v[nt] = i2; j2v[nt] = j2;
        rid2v[nt] = region3(wwh * 7 + i2) * 3 + region3(www * 7 + j2);
      }
      float den[2][4];
      u16* pb = uni + h2 * 4864;   // P[64][76] for this head
#pragma unroll
      for (int mt2 = 0; mt2 < 2; ++mt2) {
#pragma unroll
        for (int rg = 0; rg < 4; ++rg) {
          int row = (half * 2 + mt2) * 16 + quad * 4 + rg;
          int rowc = row < 49 ? row : 48;
          int qi = rowc / 7, qj = rowc - qi * 7;
          int rid1 = region3(wwh * 7 + qi) * 3 + region3(www * 7 + qj);
          float v4[4];
#pragma unroll
          for (int nt = 0; nt < 4; ++nt) {
            if (colv[nt] < 49) {
              float sv = s[mt2][nt][rg] * 0.17677669529663689f;
              sv += btab[((qi - i2v[nt] + 6) * 13 + (qj - j2v[nt] + 6)) * 12 + head];
              if (rid2v[nt] != rid1) sv -= 100.f;
              v4[nt] = sv;
            } else v4[nt] = -1e30f;
          }
          float m = fmaxf(fmaxf(v4[0], v4[1]), fmaxf(v4[2], v4[3]));
#pragma unroll
          for (int off = 1; off < 16; off <<= 1) m = fmaxf(m, __shfl_xor(m, off));
          float p[4]; float sum = 0.f;
#pragma unroll
          for (int nt = 0; nt < 4; ++nt) { p[nt] = __expf(v4[nt] - m); sum += p[nt]; }
#pragma unroll
          for (int off = 1; off < 16; off <<= 1) sum += __shfl_xor(sum, off);
          den[mt2][rg] = sum;
#pragma unroll
          for (int nt = 0; nt < 4; ++nt)
            pb[row * 76 + nt * 16 + r16] = f2bf(p[nt]);
        }
      }
      f32x4 o[2][2];
#pragma unroll
      for (int a = 0; a < 2; ++a)
#pragma unroll
        for (int c = 0; c < 2; ++c) o[a][c] = (f32x4){0.f, 0.f, 0.f, 0.f};
#pragma unroll
      for (int kc = 0; kc < 2; ++kc) {
        bf16x8 ap[2], bv[2];
#pragma unroll
        for (int mt2 = 0; mt2 < 2; ++mt2)
          ap[mt2] = *(const bf16x8*)&pb[((half * 2 + mt2) * 16 + r16) * 76 + kc * 32 + quad * 8];
#pragma unroll
        for (int nt = 0; nt < 2; ++nt)
          bv[nt] = *(const bf16x8*)&vt[h2 * 2432 + (nt * 16 + r16) * 76 + kc * 32 + quad * 8];
#pragma unroll
        for (int nt = 0; nt < 2; ++nt)
#pragma unroll
          for (int mt2 = 0; mt2 < 2; ++mt2)
            o[mt2][nt] = __builtin_amdgcn_mfma_f32_16x16x32_bf16(ap[mt2], bv[nt], o[mt2][nt], 0, 0, 0);
      }
#pragma unroll
      for (int mt2 = 0; mt2 < 2; ++mt2) {
#pragma unroll
        for (int rg = 0; rg < 4; ++rg) {
          int row = (half * 2 + mt2) * 16 + quad * 4 + rg;
          if (row < 49) {
            float inv = 1.f / den[mt2][rg];
            int qi = row / 7, qj = row - qi * 7;
            int h  = wwh * 7 + qi + 3; if (h  >= 28) h  -= 28;
            int w2 = www * 7 + qj + 3; if (w2 >= 28) w2 -= 28;
            float* orow = out + ((size_t)(bimg * 784 + h * 28 + w2)) * 384 + head * 32;
#pragma unroll
            for (int nt = 0; nt < 2; ++nt)
              orow[nt * 16 + r16] = o[mt2][nt][rg] * inv;
          }
        }
      }
    }
    __syncthreads();
  }
}

// ---------------------------------------------------------------------------
// K2+K3 fused: proj + residual + LN2 + FC1 + GELU + FC2 + residual.
// M=64 rows/block. acc2 initialized by proj+proj_b+x (same fragment layout
// as FC2 accumulator); xr never goes to global. LDS = xs 50K + hs 25.6K.
// ---------------------------------------------------------------------------
template<bool BF>
__global__ __launch_bounds__(256, 2) void pm_kernel(
    const float* attn, const void* __restrict__ proj_w, const float* __restrict__ proj_b,
    const float* __restrict__ x,
    const float* __restrict__ n2w, const float* __restrict__ n2b,
    const void* __restrict__ fc1_w, const float* __restrict__ fc1_b,
    const void* __restrict__ fc2_w, const float* __restrict__ fc2_b,
    float* outp)
{
  __shared__ __align__(16) u16 xs[64 * 392];   // 50,176 B: attn stage, then xr bf16
  __shared__ __align__(16) u16 hs[64 * 200];   // 25,600 B: one 192-col hidden chunk
  __shared__ float mustd[128];
  const int tid  = threadIdx.x;
  const int lane = tid & 63;
  const int wave = tid >> 6;
  const int quad = lane >> 4;
  const int r16  = lane & 15;
  const int bm   = blockIdx.x * 64;

  // stage attn -> xs (bf16)
  for (int e = tid * 8; e < 64 * 384; e += 2048) {
    int r = e / 384, c = e - (e / 384) * 384;
    *(uint4*)&xs[r * 392 + c] = pack8f(attn + (size_t)(bm + r) * 384 + c);
  }
  __syncthreads();

  // ---- proj GEMM -> acc2 (doubles as FC2 accumulator) ----
  f32x4 acc2[4][6];
#pragma unroll
  for (int a = 0; a < 4; ++a)
#pragma unroll
    for (int c = 0; c < 6; ++c) acc2[a][c] = (f32x4){0.f, 0.f, 0.f, 0.f};

  auto loadBp = [&](int nt, int kt) -> bf16x8 {
    if constexpr (BF) {
      return *(const bf16x8*)((const u16*)proj_w +
             ((((size_t)(wave * 6 + nt)) * 12 + kt) << 9) + r16 * 32 + quad * 8);
    } else {
      int n = wave * 96 + nt * 16 + r16;
      return ldw8((const float*)proj_w + (size_t)n * 384 + kt * 32 + quad * 8);
    }
  };
  {
    bf16x8 bc[6];
#pragma unroll
    for (int nt = 0; nt < 6; ++nt) bc[nt] = loadBp(nt, 0);
    for (int kt = 0; kt < 12; ++kt) {
      bf16x8 bn[6];
      if (kt < 11) {
#pragma unroll
        for (int nt = 0; nt < 6; ++nt) bn[nt] = loadBp(nt, kt + 1);
      }
      bf16x8 af[4];
#pragma unroll
      for (int mt = 0; mt < 4; ++mt)
        af[mt] = *(const bf16x8*)&xs[(mt * 16 + r16) * 392 + kt * 32 + quad * 8];
#pragma unroll
      for (int nt = 0; nt < 6; ++nt)
#pragma unroll
        for (int mt = 0; mt < 4; ++mt)
          acc2[mt][nt] = __builtin_amdgcn_mfma_f32_16x16x32_bf16(af[mt], bc[nt], acc2[mt][nt], 0, 0, 0);
      if (kt < 11) {
#pragma unroll
        for (int nt = 0; nt < 6; ++nt) bc[nt] = bn[nt];
      }
    }
  }
  // epilogue: acc2 = proj + proj_b + x  (xr, fp32, stays in registers)
#pragma unroll
  for (int mt = 0; mt < 4; ++mt) {
#pragma unroll
    for (int nt = 0; nt < 6; ++nt) {
#pragma unroll
      for (int rg = 0; rg < 4; ++rg) {
        int gm = bm + mt * 16 + quad * 4 + rg;
        int gn = wave * 96 + nt * 16 + r16;
        acc2[mt][nt][rg] += proj_b[gn] + x[(size_t)gm * 384 + gn];
      }
    }
  }
  __syncthreads();   // all proj GEMM reads of xs complete

  // write xr (bf16) into xs for LN2
#pragma unroll
  for (int mt = 0; mt < 4; ++mt) {
#pragma unroll
    for (int nt = 0; nt < 6; ++nt) {
#pragma unroll
      for (int rg = 0; rg < 4; ++rg) {
        int row = mt * 16 + quad * 4 + rg;
        int col = wave * 96 + nt * 16 + r16;
        xs[row * 392 + col] = f2bf(acc2[mt][nt][rg]);
      }
    }
  }
  __syncthreads();

  // LN2 stats
  for (int r = wave; r < 64; r += 4) {
    float v[6]; float s = 0.f;
#pragma unroll
    for (int k = 0; k < 6; ++k) { v[k] = bf2f(xs[r * 392 + lane + k * 64]); s += v[k]; }
#pragma unroll
    for (int off = 32; off; off >>= 1) s += __shfl_xor(s, off);
    float mu = s * (1.f / 384.f);
    float vs = 0.f;
#pragma unroll
    for (int k = 0; k < 6; ++k) { float d = v[k] - mu; vs += d * d; }
#pragma unroll
    for (int off = 32; off; off >>= 1) vs += __shfl_xor(vs, off);
    if (lane == 0) { mustd[r] = mu; mustd[64 + r] = rsqrtf(vs * (1.f / 384.f) + 1e-5f); }
  }
  __syncthreads();

  // normalize in place
  for (int e = tid * 8; e < 64 * 384; e += 2048) {
    int r = e / 384, c = e - (e / 384) * 384;
    float mu = mustd[r], rs = mustd[64 + r];
    float v[8];
    unpack8(*(uint4*)&xs[r * 392 + c], v);
    float4 w0 = *(const float4*)(n2w + c), w1 = *(const float4*)(n2w + c + 4);
    float4 b0 = *(const float4*)(n2b + c), b1 = *(const float4*)(n2b + c + 4);
    float wv[8] = {w0.x, w0.y, w0.z, w0.w, w1.x, w1.y, w1.z, w1.w};
    float bv[8] = {b0.x, b0.y, b0.z, b0.w, b1.x, b1.y, b1.z, b1.w};
    unsigned pk[4];
#pragma unroll
    for (int i = 0; i < 4; ++i) {
      u16 a = f2bf((v[2*i]   - mu) * rs * wv[2*i]   + bv[2*i]);
      u16 b = f2bf((v[2*i+1] - mu) * rs * wv[2*i+1] + bv[2*i+1]);
      pk[i] = (unsigned)a | ((unsigned)b << 16);
    }
    *(uint4*)&xs[r * 392 + c] = make_uint4(pk[0], pk[1], pk[2], pk[3]);
  }
  __syncthreads();

  // ---- hidden chunks: FC1 -> GELU -> FC2 accumulate into acc2 ----
  for (int hc = 0; hc < 8; ++hc) {
    f32x4 acc1[4][3];
#pragma unroll
    for (int a = 0; a < 4; ++a)
#pragma unroll
      for (int c = 0; c < 3; ++c) acc1[a][c] = (f32x4){0.f, 0.f, 0.f, 0.f};

    auto loadB1 = [&](int nt, int kt) -> bf16x8 {
      if constexpr (BF) {
        int rt = hc * 12 + wave * 3 + nt;
        return *(const bf16x8*)((const u16*)fc1_w +
               ((((size_t)rt) * 12 + kt) << 9) + r16 * 32 + quad * 8);
      } else {
        int ng = hc * 192 + wave * 48 + nt * 16 + r16;
        return ldw8((const float*)fc1_w + (size_t)ng * 384 + kt * 32 + quad * 8);
      }
    };
    {
      bf16x8 bc[3];
#pragma unroll
      for (int nt = 0; nt < 3; ++nt) bc[nt] = loadB1(nt, 0);
      for (int kt = 0; kt < 12; ++kt) {
        bf16x8 bn[3];
        if (kt < 11) {
#pragma unroll
          for (int nt = 0; nt < 3; ++nt) bn[nt] = loadB1(nt, kt + 1);
        }
        bf16x8 af[4];
#pragma unroll
        for (int mt = 0; mt < 4; ++mt)
          af[mt] = *(const bf16x8*)&xs[(mt * 16 + r16) * 392 + kt * 32 + quad * 8];
#pragma unroll
        for (int nt = 0; nt < 3; ++nt)
#pragma unroll
          for (int mt = 0; mt < 4; ++mt)
            acc1[mt][nt] = __builtin_amdgcn_mfma_f32_16x16x32_bf16(af[mt], bc[nt], acc1[mt][nt], 0, 0, 0);
        if (kt < 11) {
#pragma unroll
          for (int nt = 0; nt < 3; ++nt) bc[nt] = bn[nt];
        }
      }
    }
    __syncthreads();   // prev chunk's FC2 reads of hs complete
#pragma unroll
    for (int mt = 0; mt < 4; ++mt) {
#pragma unroll
      for (int nt = 0; nt < 3; ++nt) {
#pragma unroll
        for (int rg = 0; rg < 4; ++rg) {
          int row = mt * 16 + quad * 4 + rg;
          int nl  = wave * 48 + nt * 16 + r16;
          float v = acc1[mt][nt][rg] + fc1_b[hc * 192 + nl];
          hs[row * 200 + nl] = f2bf(gelu_f(v));
        }
      }
    }
    __syncthreads();
    auto loadB2 = [&](int nt, int kk) -> bf16x8 {
      if constexpr (BF) {
        int rt = wave * 6 + nt;
        return *(const bf16x8*)((const u16*)fc2_w +
               ((((size_t)rt) * 48 + hc * 6 + kk) << 9) + r16 * 32 + quad * 8);
      } else {
        int n = wave * 96 + nt * 16 + r16;
        return ldw8((const float*)fc2_w + (size_t)n * 1536 + hc * 192 + kk * 32 + quad * 8);
      }
    };
    {
      bf16x8 bc[6];
#pragma unroll
      for (int nt = 0; nt < 6; ++nt) bc[nt] = loadB2(nt, 0);
      for (int kk = 0; kk < 6; ++kk) {
        bf16x8 bn[6];
        if (kk < 5) {
#pragma unroll
          for (int nt = 0; nt < 6; ++nt) bn[nt] = loadB2(nt, kk + 1);
        }
        bf16x8 af[4];
#pragma unroll
        for (int mt = 0; mt < 4; ++mt)
          af[mt] = *(const bf16x8*)&hs[(mt * 16 + r16) * 200 + kk * 32 + quad * 8];
#pragma unroll
        for (int nt = 0; nt < 6; ++nt)
#pragma unroll
          for (int mt = 0; mt < 4; ++mt)
            acc2[mt][nt] = __builtin_amdgcn_mfma_f32_16x16x32_bf16(af[mt], bc[nt], acc2[mt][nt], 0, 0, 0);
        if (kk < 5) {
#pragma unroll
          for (int nt = 0; nt < 6; ++nt) bc[nt] = bn[nt];
        }
      }
    }
  }

  // final write: out = xr + mlp = acc2 + fc2_b (single store, no read)
#pragma unroll
  for (int mt = 0; mt < 4; ++mt) {
#pragma unroll
    for (int nt = 0; nt < 6; ++nt) {
#pragma unroll
      for (int rg = 0; rg < 4; ++rg) {
        int gm = bm + mt * 16 + quad * 4 + rg;
        int gn = wave * 96 + nt * 16 + r16;
        outp[(size_t)gm * 384 + gn] = acc2[mt][nt][rg] + fc2_b[gn];
      }
    }
  }
}

// ---------------------------------------------------------------------------
extern "C" void kernel_launch(void* const* d_in, const int* in_sizes, int n_in,
                              void* d_out, int out_size, void* d_ws, size_t ws_size,
                              hipStream_t stream) {
  const float* x      = (const float*)d_in[0];
  const float* n1w    = (const float*)d_in[1];
  const float* n1b    = (const float*)d_in[2];
  const float* qkv_w  = (const float*)d_in[3];
  const float* qkv_b  = (const float*)d_in[4];
  const float* proj_w = (const float*)d_in[5];
  const float* proj_b = (const float*)d_in[6];
  const float* btab   = (const float*)d_in[7];
  const float* n2w    = (const float*)d_in[8];
  const float* n2b    = (const float*)d_in[9];
  const float* fc1_w  = (const float*)d_in[10];
  const float* fc1_b  = (const float*)d_in[11];
  const float* fc2_w  = (const float*)d_in[12];
  const float* fc2_b  = (const float*)d_in[13];

  float* dout = (float*)d_out;
  (void)in_sizes; (void)n_in; (void)out_size;

  const size_t NQ = 442368, NP = 147456, N1 = 589824, N2 = 589824;
  const size_t need = (NQ + NP + N1 + N2) * sizeof(u16);   // 3,538,944 B

  if (d_ws && ws_size >= need) {
    u16* wq = (u16*)d_ws;
    u16* wp = wq + NQ;
    u16* w1 = wp + NP;
    u16* w2 = w1 + N1;
    repack_kernel<<<(int)((NQ / 8 + 255) / 256), 256, 0, stream>>>(qkv_w,  wq, 1152, 384);
    repack_kernel<<<(int)((NP / 8 + 255) / 256), 256, 0, stream>>>(proj_w, wp, 384, 384);
    repack_kernel<<<(int)((N1 / 8 + 255) / 256), 256, 0, stream>>>(fc1_w,  w1, 1536, 384);
    repack_kernel<<<(int)((N2 / 8 + 255) / 256), 256, 0, stream>>>(fc2_w,  w2, 384, 1536);

    win_attn_kernel<true><<<1024, 256, 0, stream>>>(x, n1w, n1b, wq, qkv_b, btab, dout);
    pm_kernel<true><<<784, 256, 0, stream>>>(dout, wp, proj_b, x,
                                             n2w, n2b, w1, fc1_b, w2, fc2_b, dout);
  } else {
    win_attn_kernel<false><<<1024, 256, 0, stream>>>(x, n1w, n1b, qkv_w, qkv_b, btab, dout);
    pm_kernel<false><<<784, 256, 0, stream>>>(dout, proj_w, proj_b, x,
                                              n2w, n2b, fc1_w, fc1_b, fc2_w, fc2_b, dout);
  }
}